// Round 1
// baseline (2420.630 us; speedup 1.0000x reference)
//
#include <hip/hip_runtime.h>
#include <cstdint>
#include <cstddef>

#define N_NODES 4096
#define F_INF   3000
#define HIDC    256
#define NEDGE   65536
#define POOLH   128

__device__ inline float lrelu(float x){ return x > 0.f ? x : 0.2f*x; }

// ---------------- CSR build ----------------
__global__ void k_deg(const int* __restrict__ dst, int* __restrict__ deg){
  int e = blockIdx.x*256 + threadIdx.x;
  if (e < NEDGE) atomicAdd(&deg[dst[e]], 1);
}

__global__ void k_scan(const int* __restrict__ deg, int* __restrict__ off){
  __shared__ int sm[1024];
  int tid = threadIdx.x;
  int v0=deg[tid*4], v1=deg[tid*4+1], v2=deg[tid*4+2], v3=deg[tid*4+3];
  int s = v0+v1+v2+v3;
  sm[tid]=s; __syncthreads();
  for (int d=1; d<1024; d<<=1){
    int t = (tid>=d)? sm[tid-d] : 0;
    __syncthreads();
    sm[tid] += t;
    __syncthreads();
  }
  int run = sm[tid]-s;
  off[tid*4+0]=run; run+=v0;
  off[tid*4+1]=run; run+=v1;
  off[tid*4+2]=run; run+=v2;
  off[tid*4+3]=run; run+=v3;
  if (tid==1023) off[N_NODES]=run;
}

__global__ void k_fill(const int* __restrict__ ei, const float* __restrict__ ew,
                       const int* __restrict__ off, int* __restrict__ cursor,
                       int* __restrict__ csr_src, float* __restrict__ csr_w){
  int e = blockIdx.x*256+threadIdx.x;
  if (e >= NEDGE) return;
  int d = ei[NEDGE + e];
  int slot = off[d] + atomicAdd(&cursor[d],1);
  csr_src[slot] = ei[e];
  csr_w[slot] = ew[e];
}

// ---------------- fp32 tiled GEMM: C[M,N] = A[M,K] @ B[K,N] ----------------
// AINT: A is int32 mask, converted to 0/1 float on load.
template<bool AINT>
__global__ __launch_bounds__(256) void k_gemm(const void* __restrict__ Av,
                       const float* __restrict__ B, float* __restrict__ C,
                       int M, int Nn, int K){
  const int BM=64, BN=64, BK=16;
  __shared__ __align__(16) float As[BK][BM+4];
  __shared__ __align__(16) float Bs[BK][BN];
  int bm = blockIdx.y*BM, bn = blockIdx.x*BN;
  int tid = threadIdx.x;
  int tx = tid & 15, ty = tid >> 4;
  const float* Af = (const float*)Av;
  const int*   Ai = (const int*)Av;
  float acc[4][4]={};
  for (int k0=0;k0<K;k0+=BK){
    #pragma unroll
    for (int i=0;i<4;i++){
      int idx = tid + i*256;
      int m = idx>>4, k = idx&15;
      int gr = bm+m, gk = k0+k;
      float v = 0.f;
      if (gk < K) v = AINT ? (Ai[(size_t)gr*K+gk] ? 1.f : 0.f) : Af[(size_t)gr*K+gk];
      As[k][m] = v;
    }
    #pragma unroll
    for (int i=0;i<4;i++){
      int idx = tid + i*256;
      int k = idx>>6, n = idx&63;
      int gk = k0+k, gn = bn+n;
      Bs[k][n] = (gk<K && gn<Nn) ? B[(size_t)gk*Nn+gn] : 0.f;
    }
    __syncthreads();
    #pragma unroll
    for (int k=0;k<BK;k++){
      float4 a = *(const float4*)&As[k][ty*4];
      float4 b = *(const float4*)&Bs[k][tx*4];
      float av[4]={a.x,a.y,a.z,a.w}, bv[4]={b.x,b.y,b.z,b.w};
      #pragma unroll
      for (int i=0;i<4;i++)
        #pragma unroll
        for (int j=0;j<4;j++) acc[i][j] += av[i]*bv[j];
    }
    __syncthreads();
  }
  #pragma unroll
  for (int i=0;i<4;i++){
    int gr = bm + ty*4 + i;
    if (gr >= M) continue;
    int gn = bn + tx*4;
    if (gn + 3 < Nn){
      float4 r; r.x=acc[i][0]; r.y=acc[i][1]; r.z=acc[i][2]; r.w=acc[i][3];
      *(float4*)&C[(size_t)gr*Nn+gn] = r;
    } else {
      #pragma unroll
      for (int j=0;j<4;j++) if (gn+j<Nn) C[(size_t)gr*Nn+gn+j] = acc[i][j];
    }
  }
}

// ---------------- GAT layer 1 (4 heads x 64 ch) ----------------
__global__ void k_scores1(const float* __restrict__ h1, const float* __restrict__ a_src,
                          const float* __restrict__ a_dst, float* __restrict__ s_src,
                          float* __restrict__ s_dst){
  int n = blockIdx.x, c = threadIdx.x;           // 256 threads, wave w == head w
  float v = h1[(size_t)n*HIDC + c];
  float vs = v * a_src[c];
  float vd = v * a_dst[c];
  #pragma unroll
  for (int o=32;o>0;o>>=1){ vs += __shfl_down(vs,o); vd += __shfl_down(vd,o); }
  if ((c&63)==0){ int h=c>>6; s_src[n*4+h]=vs; s_dst[n*4+h]=vd; }
}

__global__ void k_gat1(const float* __restrict__ h1, const float* __restrict__ s_src,
                       const float* __restrict__ s_dst, const int* __restrict__ off,
                       const int* __restrict__ csr_src, const float* __restrict__ csr_w,
                       const float* __restrict__ b1, float* __restrict__ z){
  int n = blockIdx.x, c = threadIdx.x, h = c>>6;
  int o0 = off[n], o1 = off[n+1];
  float sd = s_dst[n*4+h];
  float m = -1e30f;
  for (int t=o0;t<o1;t++){
    int s = csr_src[t];
    m = fmaxf(m, lrelu(s_src[s*4+h]+sd));
  }
  float denom=0.f, acc=0.f;
  for (int t=o0;t<o1;t++){
    int s = csr_src[t];
    float w = expf(lrelu(s_src[s*4+h]+sd)-m)*csr_w[t];
    denom += w;
    acc += w * h1[(size_t)s*HIDC + c];
  }
  float res = acc/(denom+1e-16f) + b1[c];
  z[(size_t)n*HIDC+c] = fmaxf(res, 0.f);
}

// ---------------- GAT layer 2 (1 head x 3000 ch) ----------------
__global__ void k_scores2(const float* __restrict__ h2, const float* __restrict__ a_src,
                          const float* __restrict__ a_dst, float* __restrict__ s_src,
                          float* __restrict__ s_dst){
  __shared__ float sm[8];
  int n = blockIdx.x, tid = threadIdx.x;
  const float* row = h2 + (size_t)n*F_INF;
  float vs=0.f, vd=0.f;
  for (int c=tid;c<F_INF;c+=256){ float v=row[c]; vs += v*a_src[c]; vd += v*a_dst[c]; }
  #pragma unroll
  for (int o=32;o>0;o>>=1){ vs+=__shfl_down(vs,o); vd+=__shfl_down(vd,o); }
  int lane=tid&63, w=tid>>6;
  if (lane==0){ sm[w]=vs; sm[4+w]=vd; }
  __syncthreads();
  if (tid==0) s_src[n]=sm[0]+sm[1]+sm[2]+sm[3];
  if (tid==1) s_dst[n]=sm[4]+sm[5]+sm[6]+sm[7];
}

__global__ void k_gat2(const float* __restrict__ h2, const float* __restrict__ s_src,
                       const float* __restrict__ s_dst, const int* __restrict__ off,
                       const int* __restrict__ csr_src, const float* __restrict__ csr_w,
                       const float* __restrict__ b2, float* __restrict__ hout){
  int n = blockIdx.x, tid = threadIdx.x;
  int o0=off[n], o1=off[n+1];
  float sd = s_dst[n];
  float m=-1e30f;
  for (int t=o0;t<o1;t++) m = fmaxf(m, lrelu(s_src[csr_src[t]]+sd));
  float denom=0.f;
  float acc[12];
  #pragma unroll
  for (int k=0;k<12;k++) acc[k]=0.f;
  for (int t=o0;t<o1;t++){
    int s=csr_src[t];
    float w = expf(lrelu(s_src[s]+sd)-m)*csr_w[t];
    denom += w;
    const float* row = h2 + (size_t)s*F_INF;
    #pragma unroll
    for (int k=0;k<12;k++){
      int c = tid + k*256;
      if (c < F_INF) acc[k] += w*row[c];
    }
  }
  float inv = 1.f/(denom+1e-16f);
  #pragma unroll
  for (int k=0;k<12;k++){
    int c = tid + k*256;
    if (c<F_INF) hout[(size_t)n*F_INF+c] = acc[k]*inv + b2[c];
  }
}

// ---------------- attention pooling ----------------
__global__ void k_pool(const float* __restrict__ emb, const float* __restrict__ w1,
                       const float* __restrict__ b1, const float* __restrict__ w2,
                       const float* __restrict__ b2, float* __restrict__ scores){
  __shared__ float ze[HIDC];
  __shared__ float red[POOLH];
  int n = blockIdx.x, t = threadIdx.x; // 128 threads
  ze[t]       = emb[(size_t)n*HIDC + t];
  ze[t+128]   = emb[(size_t)n*HIDC + t + 128];
  __syncthreads();
  float acc = b1[t];
  for (int d=0; d<HIDC; d++) acc += ze[d]*w1[d*POOLH + t];
  float hidden = fmaxf(acc, 0.f);
  red[t] = hidden * w2[t];
  __syncthreads();
  for (int s=64; s>0; s>>=1){
    if (t < s) red[t] += red[t+s];
    __syncthreads();
  }
  if (t==0) scores[n] = red[0] + b2[0];
}

__global__ void k_maxred(const float* __restrict__ s, float* __restrict__ M){
  __shared__ float sm[16];
  int tid=threadIdx.x;
  float m=-1e30f;
  for (int i=tid;i<N_NODES;i+=1024) m=fmaxf(m,s[i]);
  #pragma unroll
  for (int o=32;o>0;o>>=1) m=fmaxf(m,__shfl_down(m,o));
  if ((tid&63)==0) sm[tid>>6]=m;
  __syncthreads();
  if (tid==0){
    float mm=sm[0];
    for (int i=1;i<16;i++) mm=fmaxf(mm,sm[i]);
    M[0]=mm;
  }
}

__global__ void k_p(const float* __restrict__ s, const float* __restrict__ M,
                    float* __restrict__ p){
  int i=blockIdx.x*256+threadIdx.x;
  if (i<N_NODES) p[i]=expf(s[i]-M[0]);
}

__global__ void k_q(const float* __restrict__ p, const float* __restrict__ emb,
                    float* __restrict__ q){
  int i = blockIdx.x*256+threadIdx.x;   // N*HID total
  int n = i>>8;
  q[i] = p[n]*emb[i];
}

__global__ void k_denom(const int* __restrict__ mask, const float* __restrict__ p,
                        float* __restrict__ dn){
  __shared__ float sm[4];
  int i=blockIdx.x, tid=threadIdx.x;
  const int* row = mask + (size_t)i*N_NODES;
  float s=0.f;
  for (int j=tid;j<N_NODES;j+=256) s += row[j] ? p[j] : 0.f;
  #pragma unroll
  for (int o=32;o>0;o>>=1) s+=__shfl_down(s,o);
  if ((tid&63)==0) sm[tid>>6]=s;
  __syncthreads();
  if (tid==0) dn[i]=sm[0]+sm[1]+sm[2]+sm[3];
}

__global__ void k_gfin(const float* __restrict__ G, const float* __restrict__ dn,
                       float* __restrict__ g){
  __shared__ float sm[4];
  __shared__ float tot;
  int n=blockIdx.x, c=threadIdx.x;
  float gp = G[(size_t)n*HIDC+c] / dn[n];
  float v = gp*gp;
  #pragma unroll
  for (int o=32;o>0;o>>=1) v+=__shfl_down(v,o);
  if ((c&63)==0) sm[c>>6]=v;
  __syncthreads();
  if (c==0) tot = sm[0]+sm[1]+sm[2]+sm[3];
  __syncthreads();
  float nrm = sqrtf(tot);
  float x = gp/fmaxf(nrm,1e-12f);
  g[(size_t)n*HIDC+c]=1.f/(1.f+expf(-x));
}

// ---------------- discriminator ----------------
__global__ void k_tr(const float* __restrict__ W, float* __restrict__ WT){
  int d = blockIdx.x, c = threadIdx.x;
  WT[d*HIDC + c] = W[c*HIDC + d];
}

__global__ void k_disc(const float* __restrict__ z, const float* __restrict__ za,
                       const float* __restrict__ V, const float* __restrict__ Va,
                       const float* __restrict__ bbp, const float* __restrict__ biasp,
                       float* __restrict__ ret, float* __restrict__ ret_a){
  __shared__ float sm[16];
  int n=blockIdx.x, c=threadIdx.x;
  float ez = z[(size_t)n*HIDC+c], ea = za[(size_t)n*HIDC+c];
  float v  = V[(size_t)n*HIDC+c], va = Va[(size_t)n*HIDC+c];
  float p1=ez*v, p2=ea*v, p3=ea*va, p4=ez*va;
  #pragma unroll
  for (int o=32;o>0;o>>=1){
    p1+=__shfl_down(p1,o); p2+=__shfl_down(p2,o);
    p3+=__shfl_down(p3,o); p4+=__shfl_down(p4,o);
  }
  int lane=c&63, w=c>>6;
  if (lane==0){ sm[w]=p1; sm[4+w]=p2; sm[8+w]=p3; sm[12+w]=p4; }
  __syncthreads();
  if (c==0){
    float add = bbp[0]+biasp[0];
    ret[n*2+0]   = sm[0]+sm[1]+sm[2]+sm[3]   + add;
    ret[n*2+1]   = sm[4]+sm[5]+sm[6]+sm[7]   + add;
    ret_a[n*2+0] = sm[8]+sm[9]+sm[10]+sm[11] + add;
    ret_a[n*2+1] = sm[12]+sm[13]+sm[14]+sm[15] + add;
  }
}

extern "C" void kernel_launch(void* const* d_in, const int* in_sizes, int n_in,
                              void* d_out, int out_size, void* d_ws, size_t ws_size,
                              hipStream_t stream){
  (void)in_sizes; (void)n_in; (void)out_size; (void)ws_size;
  const float* feat   = (const float*)d_in[0];
  const float* feat_a = (const float*)d_in[1];
  const int*   ei     = (const int*)d_in[2];
  const float* ew     = (const float*)d_in[3];
  const int*   mask   = (const int*)d_in[4];
  const float* W1     = (const float*)d_in[5];
  const float* a_src1 = (const float*)d_in[6];
  const float* a_dst1 = (const float*)d_in[7];
  const float* b1     = (const float*)d_in[8];
  const float* W2     = (const float*)d_in[9];
  const float* a_src2 = (const float*)d_in[10];
  const float* a_dst2 = (const float*)d_in[11];
  const float* b2     = (const float*)d_in[12];
  const float* pw1    = (const float*)d_in[13];
  const float* pb1    = (const float*)d_in[14];
  const float* pw2    = (const float*)d_in[15];
  const float* pb2    = (const float*)d_in[16];
  const float* dw     = (const float*)d_in[17];
  const float* dbb    = (const float*)d_in[18];
  const float* dbias  = (const float*)d_in[19];

  float* out  = (float*)d_out;
  float* z    = out;                                  // hidden_emb [N,HID]
  float* hout = out + (size_t)N_NODES*HIDC;           // h [N,F_IN]
  float* ret  = hout + (size_t)N_NODES*F_INF;         // [N,2]
  float* ret_a= ret + (size_t)N_NODES*2;              // [N,2]

  float* ws = (float*)d_ws;
  size_t o=0;
  float* h2  = ws+o; o += (size_t)N_NODES*F_INF;
  float* h1  = ws+o; o += (size_t)N_NODES*HIDC;
  float* h1a = ws+o; o += (size_t)N_NODES*HIDC;
  float* za  = ws+o; o += (size_t)N_NODES*HIDC;
  float* q   = ws+o; o += (size_t)N_NODES*HIDC;
  float* G   = ws+o; o += (size_t)N_NODES*HIDC;
  float* gv  = ws+o; o += (size_t)N_NODES*HIDC;
  float* gva = ws+o; o += (size_t)N_NODES*HIDC;
  float* V   = ws+o; o += (size_t)N_NODES*HIDC;
  float* Va  = ws+o; o += (size_t)N_NODES*HIDC;
  float* W0T = ws+o; o += (size_t)HIDC*HIDC;
  float* ss1 = ws+o; o += N_NODES*4;
  float* sd1 = ws+o; o += N_NODES*4;
  float* ss2 = ws+o; o += N_NODES;
  float* sd2 = ws+o; o += N_NODES;
  float* scA = ws+o; o += N_NODES;
  float* scB = ws+o; o += N_NODES;
  float* pv  = ws+o; o += N_NODES;
  float* dnv = ws+o; o += N_NODES;
  float* Mb  = ws+o; o += 64;
  int* deg    = (int*)(ws+o); o += N_NODES;
  int* off    = (int*)(ws+o); o += N_NODES+64;
  int* cursor = (int*)(ws+o); o += N_NODES;
  int* csrc   = (int*)(ws+o); o += NEDGE;
  float* csw  = ws+o; o += NEDGE;

  // CSR build
  hipMemsetAsync(deg, 0, N_NODES*sizeof(int), stream);
  hipMemsetAsync(cursor, 0, N_NODES*sizeof(int), stream);
  k_deg<<<NEDGE/256,256,0,stream>>>(ei+NEDGE, deg);
  k_scan<<<1,1024,0,stream>>>(deg, off);
  k_fill<<<NEDGE/256,256,0,stream>>>(ei, ew, off, cursor, csrc, csw);

  // projections
  dim3 g256(HIDC/64, N_NODES/64);
  k_gemm<false><<<g256,256,0,stream>>>(feat,   W1, h1,  N_NODES, HIDC, F_INF);
  k_gemm<false><<<g256,256,0,stream>>>(feat_a, W1, h1a, N_NODES, HIDC, F_INF);

  // GAT1 both branches
  k_scores1<<<N_NODES,256,0,stream>>>(h1, a_src1, a_dst1, ss1, sd1);
  k_gat1<<<N_NODES,256,0,stream>>>(h1, ss1, sd1, off, csrc, csw, b1, z);
  k_scores1<<<N_NODES,256,0,stream>>>(h1a, a_src1, a_dst1, ss1, sd1);
  k_gat1<<<N_NODES,256,0,stream>>>(h1a, ss1, sd1, off, csrc, csw, b1, za);

  // GAT2 (branch 1 only)
  dim3 g3000((F_INF+63)/64, N_NODES/64);
  k_gemm<false><<<g3000,256,0,stream>>>(z, W2, h2, N_NODES, F_INF, HIDC);
  k_scores2<<<N_NODES,256,0,stream>>>(h2, a_src2, a_dst2, ss2, sd2);
  k_gat2<<<N_NODES,256,0,stream>>>(h2, ss2, sd2, off, csrc, csw, b2, hout);

  // pooling scores
  k_pool<<<N_NODES,128,0,stream>>>(z,  pw1, pb1, pw2, pb2, scA);
  k_pool<<<N_NODES,128,0,stream>>>(za, pw1, pb1, pw2, pb2, scB);

  // branch 1 pooling
  k_maxred<<<1,1024,0,stream>>>(scA, Mb);
  k_p<<<N_NODES/256,256,0,stream>>>(scA, Mb, pv);
  k_q<<<(N_NODES*HIDC)/256,256,0,stream>>>(pv, z, q);
  k_denom<<<N_NODES,256,0,stream>>>(mask, pv, dnv);
  k_gemm<true><<<g256,256,0,stream>>>(mask, q, G, N_NODES, HIDC, N_NODES);
  k_gfin<<<N_NODES,256,0,stream>>>(G, dnv, gv);
  // branch a pooling
  k_maxred<<<1,1024,0,stream>>>(scB, Mb);
  k_p<<<N_NODES/256,256,0,stream>>>(scB, Mb, pv);
  k_q<<<(N_NODES*HIDC)/256,256,0,stream>>>(pv, za, q);
  k_denom<<<N_NODES,256,0,stream>>>(mask, pv, dnv);
  k_gemm<true><<<g256,256,0,stream>>>(mask, q, G, N_NODES, HIDC, N_NODES);
  k_gfin<<<N_NODES,256,0,stream>>>(G, dnv, gva);

  // discriminator
  k_tr<<<HIDC,HIDC,0,stream>>>(dw, W0T);
  k_gemm<false><<<g256,256,0,stream>>>(gv,  W0T, V,  N_NODES, HIDC, HIDC);
  k_gemm<false><<<g256,256,0,stream>>>(gva, W0T, Va, N_NODES, HIDC, HIDC);
  k_disc<<<N_NODES,256,0,stream>>>(z, za, V, Va, dbb, dbias, ret, ret_a);

  (void)ss2; (void)sd2;
}

// Round 2
// 671.473 us; speedup vs baseline: 3.6050x; 3.6050x over previous
//
#include <hip/hip_runtime.h>
#include <cstdint>
#include <cstddef>

#define N_NODES 4096
#define F_INF   3000
#define FPAD    3008
#define NPAD    3072
#define HIDC    256
#define NEDGE   65536
#define POOLH   128

typedef unsigned short u16;
typedef __attribute__((ext_vector_type(8))) short bf16x8;
typedef __attribute__((ext_vector_type(4))) float f32x4;

__device__ inline float lrelu(float x){ return x > 0.f ? x : 0.2f*x; }
__device__ inline u16 f2b(float f){
  uint32_t x = __builtin_bit_cast(uint32_t, f);
  uint32_t r = (x + 0x7fffu + ((x >> 16) & 1u)) >> 16;
  return (u16)r;
}
__device__ inline float b2f(u16 u){
  uint32_t x = ((uint32_t)u) << 16;
  return __builtin_bit_cast(float, x);
}
__device__ __forceinline__ void lds16(const u16* g, u16* l){
  __builtin_amdgcn_global_load_lds((const __attribute__((address_space(1))) void*)g,
                                   (__attribute__((address_space(3))) void*)l, 16, 0, 0);
}

// ---------------- CSR build ----------------
__global__ void k_deg(const int* __restrict__ dst, int* __restrict__ deg){
  int e = blockIdx.x*256 + threadIdx.x;
  if (e < NEDGE) atomicAdd(&deg[dst[e]], 1);
}

__global__ void k_scan(const int* __restrict__ deg, int* __restrict__ off){
  __shared__ int sm[1024];
  int tid = threadIdx.x;
  int v0=deg[tid*4], v1=deg[tid*4+1], v2=deg[tid*4+2], v3=deg[tid*4+3];
  int s = v0+v1+v2+v3;
  sm[tid]=s; __syncthreads();
  for (int d=1; d<1024; d<<=1){
    int t = (tid>=d)? sm[tid-d] : 0;
    __syncthreads();
    sm[tid] += t;
    __syncthreads();
  }
  int run = sm[tid]-s;
  off[tid*4+0]=run; run+=v0;
  off[tid*4+1]=run; run+=v1;
  off[tid*4+2]=run; run+=v2;
  off[tid*4+3]=run; run+=v3;
  if (tid==1023) off[N_NODES]=run;
}

__global__ void k_fill(const int* __restrict__ ei, const float* __restrict__ ew,
                       const int* __restrict__ off, int* __restrict__ cursor,
                       int* __restrict__ csr_src, float* __restrict__ csr_w){
  int e = blockIdx.x*256+threadIdx.x;
  if (e >= NEDGE) return;
  int d = ei[NEDGE + e];
  int slot = off[d] + atomicAdd(&cursor[d],1);
  csr_src[slot] = ei[e];
  csr_w[slot] = ew[e];
}

// ---------------- conversions ----------------
// f32 [R][Cin] -> bf16 [R][Cout] zero-padded
__global__ void k_cvt(const float* __restrict__ in, u16* __restrict__ out,
                      int R, int Cin, int Cout){
  size_t i = ((size_t)blockIdx.x*256 + threadIdx.x)*4;
  if (i >= (size_t)R*Cout) return;
  int r = (int)(i / Cout), c = (int)(i % Cout);
  ushort4 o;
  if (c + 3 < Cin){
    float4 v = *(const float4*)(in + (size_t)r*Cin + c);
    o.x=f2b(v.x); o.y=f2b(v.y); o.z=f2b(v.z); o.w=f2b(v.w);
  } else {
    float vs[4];
    #pragma unroll
    for (int j=0;j<4;j++) vs[j] = (c+j<Cin)? in[(size_t)r*Cin+c+j] : 0.f;
    o.x=f2b(vs[0]); o.y=f2b(vs[1]); o.z=f2b(vs[2]); o.w=f2b(vs[3]);
  }
  *(ushort4*)(out+i) = o;
}

// int mask -> bf16 0/1
__global__ void k_cvt_mask(const int* __restrict__ in, u16* __restrict__ out){
  size_t i = ((size_t)blockIdx.x*256 + threadIdx.x)*4;
  int4 v = *(const int4*)(in + i);
  ushort4 o;
  o.x = v.x ? 0x3f80 : 0; o.y = v.y ? 0x3f80 : 0;
  o.z = v.z ? 0x3f80 : 0; o.w = v.w ? 0x3f80 : 0;
  *(ushort4*)(out+i) = o;
}

// out[c][r] = in[r][c] * (scale?scale[r]:1), bf16, zero-pad outside [R][C].
// grid: (ORows/32, OCols/32); out is [ORows][OCols]
__global__ void k_trcvt(const float* __restrict__ in, u16* __restrict__ out,
                        int R, int C, int OCols, const float* __restrict__ scale){
  __shared__ float t[32][33];
  int c0 = blockIdx.x*32, r0 = blockIdx.y*32;
  int tx = threadIdx.x & 31, ty = threadIdx.x >> 5;
  #pragma unroll
  for (int i=0;i<4;i++){
    int r = r0 + ty + i*8, c = c0 + tx;
    float v = (r<R && c<C) ? in[(size_t)r*C + c] : 0.f;
    if (scale && r<R) v *= scale[r];
    t[ty+i*8][tx] = v;
  }
  __syncthreads();
  #pragma unroll
  for (int i=0;i<4;i++){
    int c = c0 + ty + i*8, r = r0 + tx;
    out[(size_t)c*OCols + r] = f2b(t[tx][ty+i*8]);
  }
}

// ---------------- bf16 MFMA GEMM: C[M,N] = A[M,K] @ B^T[N,K] ----------------
// A,B bf16 row-major with row length K (multiple of 32). 128x128 tile, 4 waves.
template<bool CBF16>
__global__ __launch_bounds__(256) void k_mgemm(const u16* __restrict__ A,
        const u16* __restrict__ B, void* __restrict__ Cv,
        int M, int Nn, int K, int ldc){
  __shared__ u16 sA[128*32];
  __shared__ u16 sB[128*32];
  const int tid = threadIdx.x;
  const int bm = blockIdx.y*128, bn = blockIdx.x*128;
  const int lane = tid & 63, w = tid >> 6;
  const int wr = w >> 1, wc = w & 1;
  const int ar = tid >> 2;            // staging row (within 64-row half)
  const int ac = (tid & 3) * 8;       // staging k-offset (elements)
  f32x4 acc[4][4] = {};

  for (int k0 = 0; k0 < K; k0 += 32){
    lds16(A + (size_t)(bm + ar)*K      + k0 + ac, &sA[(size_t)tid*8]);
    lds16(A + (size_t)(bm + 64 + ar)*K + k0 + ac, &sA[2048 + (size_t)tid*8]);
    lds16(B + (size_t)(bn + ar)*K      + k0 + ac, &sB[(size_t)tid*8]);
    lds16(B + (size_t)(bn + 64 + ar)*K + k0 + ac, &sB[2048 + (size_t)tid*8]);
    __syncthreads();
    bf16x8 af[4], bfv[4];
    #pragma unroll
    for (int m=0;m<4;m++)
      af[m] = *(const bf16x8*)&sA[(wr*64 + m*16 + (lane&15))*32 + (lane>>4)*8];
    #pragma unroll
    for (int n=0;n<4;n++)
      bfv[n] = *(const bf16x8*)&sB[(wc*64 + n*16 + (lane&15))*32 + (lane>>4)*8];
    #pragma unroll
    for (int m=0;m<4;m++)
      #pragma unroll
      for (int n=0;n<4;n++)
        acc[m][n] = __builtin_amdgcn_mfma_f32_16x16x32_bf16(af[m], bfv[n], acc[m][n], 0,0,0);
    __syncthreads();
  }

  const int rbase = bm + wr*64 + ((lane>>4)<<2);
  const int cbase = bn + wc*64 + (lane&15);
  if (CBF16){
    u16* C = (u16*)Cv;
    #pragma unroll
    for (int m=0;m<4;m++)
      #pragma unroll
      for (int n=0;n<4;n++)
        #pragma unroll
        for (int j=0;j<4;j++)
          C[(size_t)(rbase + m*16 + j)*ldc + cbase + n*16] = f2b(acc[m][n][j]);
  } else {
    float* C = (float*)Cv;
    #pragma unroll
    for (int m=0;m<4;m++)
      #pragma unroll
      for (int n=0;n<4;n++)
        #pragma unroll
        for (int j=0;j<4;j++)
          C[(size_t)(rbase + m*16 + j)*ldc + cbase + n*16] = acc[m][n][j];
  }
}

// ---------------- GAT layer 1 (4 heads x 64 ch) ----------------
__global__ void k_scores1(const float* __restrict__ h1, const float* __restrict__ a_src,
                          const float* __restrict__ a_dst, float* __restrict__ s_src,
                          float* __restrict__ s_dst){
  int n = blockIdx.x, c = threadIdx.x;
  float v = h1[(size_t)n*HIDC + c];
  float vs = v * a_src[c];
  float vd = v * a_dst[c];
  #pragma unroll
  for (int o=32;o>0;o>>=1){ vs += __shfl_down(vs,o); vd += __shfl_down(vd,o); }
  if ((c&63)==0){ int h=c>>6; s_src[n*4+h]=vs; s_dst[n*4+h]=vd; }
}

__global__ void k_gat1(const float* __restrict__ h1, const float* __restrict__ s_src,
                       const float* __restrict__ s_dst, const int* __restrict__ off,
                       const int* __restrict__ csr_src, const float* __restrict__ csr_w,
                       const float* __restrict__ b1, float* __restrict__ z){
  int n = blockIdx.x, c = threadIdx.x, h = c>>6;
  int o0 = off[n], o1 = off[n+1];
  float sd = s_dst[n*4+h];
  float m = -1e30f;
  for (int t=o0;t<o1;t++){
    int s = csr_src[t];
    m = fmaxf(m, lrelu(s_src[s*4+h]+sd));
  }
  float denom=0.f, acc=0.f;
  for (int t=o0;t<o1;t++){
    int s = csr_src[t];
    float wv = expf(lrelu(s_src[s*4+h]+sd)-m)*csr_w[t];
    denom += wv;
    acc += wv * h1[(size_t)s*HIDC + c];
  }
  float res = acc/(denom+1e-16f) + b1[c];
  z[(size_t)n*HIDC+c] = fmaxf(res, 0.f);
}

// ---------------- GAT layer 2 (1 head x 3000 ch, h2 bf16 ld=NPAD) ----------------
__global__ void k_scores2(const u16* __restrict__ h2, const float* __restrict__ a_src,
                          const float* __restrict__ a_dst, float* __restrict__ s_src,
                          float* __restrict__ s_dst){
  __shared__ float sm[8];
  int n = blockIdx.x, tid = threadIdx.x;
  const u16* row = h2 + (size_t)n*NPAD;
  float vs=0.f, vd=0.f;
  for (int c = tid*8; c < F_INF; c += 2048){
    ushort4 u0 = *(const ushort4*)(row + c);
    ushort4 u1 = *(const ushort4*)(row + c + 4);
    float f0=b2f(u0.x), f1=b2f(u0.y), f2=b2f(u0.z), f3=b2f(u0.w);
    float f4=b2f(u1.x), f5=b2f(u1.y), f6=b2f(u1.z), f7=b2f(u1.w);
    vs += f0*a_src[c]+f1*a_src[c+1]+f2*a_src[c+2]+f3*a_src[c+3]
        + f4*a_src[c+4]+f5*a_src[c+5]+f6*a_src[c+6]+f7*a_src[c+7];
    vd += f0*a_dst[c]+f1*a_dst[c+1]+f2*a_dst[c+2]+f3*a_dst[c+3]
        + f4*a_dst[c+4]+f5*a_dst[c+5]+f6*a_dst[c+6]+f7*a_dst[c+7];
  }
  #pragma unroll
  for (int o=32;o>0;o>>=1){ vs+=__shfl_down(vs,o); vd+=__shfl_down(vd,o); }
  int lane=tid&63, w=tid>>6;
  if (lane==0){ sm[w]=vs; sm[4+w]=vd; }
  __syncthreads();
  if (tid==0) s_src[n]=sm[0]+sm[1]+sm[2]+sm[3];
  if (tid==1) s_dst[n]=sm[4]+sm[5]+sm[6]+sm[7];
}

__global__ void k_gat2(const u16* __restrict__ h2, const float* __restrict__ s_src,
                       const float* __restrict__ s_dst, const int* __restrict__ off,
                       const int* __restrict__ csr_src, const float* __restrict__ csr_w,
                       const float* __restrict__ b2, float* __restrict__ hout){
  int n = blockIdx.x, tid = threadIdx.x;
  int o0=off[n], o1=off[n+1];
  float sd = s_dst[n];
  float m=-1e30f;
  for (int t=o0;t<o1;t++) m = fmaxf(m, lrelu(s_src[csr_src[t]]+sd));
  float denom=0.f;
  float acc[12];
  #pragma unroll
  for (int k=0;k<12;k++) acc[k]=0.f;
  int c0 = tid*12;
  bool act = c0 < F_INF;
  for (int t=o0;t<o1;t++){
    int s=csr_src[t];
    float wv = expf(lrelu(s_src[s]+sd)-m)*csr_w[t];
    denom += wv;
    if (act){
      const ushort4* r4 = (const ushort4*)(h2 + (size_t)s*NPAD + c0);
      #pragma unroll
      for (int v=0;v<3;v++){
        ushort4 u = r4[v];
        acc[v*4+0] += wv*b2f(u.x);
        acc[v*4+1] += wv*b2f(u.y);
        acc[v*4+2] += wv*b2f(u.z);
        acc[v*4+3] += wv*b2f(u.w);
      }
    }
  }
  float inv = 1.f/(denom+1e-16f);
  if (act){
    #pragma unroll
    for (int k=0;k<12;k++)
      hout[(size_t)n*F_INF + c0 + k] = acc[k]*inv + b2[c0+k];
  }
}

// ---------------- attention pooling ----------------
__global__ void k_pool(const float* __restrict__ emb, const float* __restrict__ w1,
                       const float* __restrict__ b1, const float* __restrict__ w2,
                       const float* __restrict__ b2, float* __restrict__ scores){
  __shared__ float ze[HIDC];
  __shared__ float red[POOLH];
  int n = blockIdx.x, t = threadIdx.x;
  ze[t]     = emb[(size_t)n*HIDC + t];
  ze[t+128] = emb[(size_t)n*HIDC + t + 128];
  __syncthreads();
  float acc = b1[t];
  for (int d=0; d<HIDC; d++) acc += ze[d]*w1[d*POOLH + t];
  float hidden = fmaxf(acc, 0.f);
  red[t] = hidden * w2[t];
  __syncthreads();
  for (int s=64; s>0; s>>=1){
    if (t < s) red[t] += red[t+s];
    __syncthreads();
  }
  if (t==0) scores[n] = red[0] + b2[0];
}

__global__ void k_maxred(const float* __restrict__ s, float* __restrict__ M){
  __shared__ float sm[16];
  int tid=threadIdx.x;
  float m=-1e30f;
  for (int i=tid;i<N_NODES;i+=1024) m=fmaxf(m,s[i]);
  #pragma unroll
  for (int o=32;o>0;o>>=1) m=fmaxf(m,__shfl_down(m,o));
  if ((tid&63)==0) sm[tid>>6]=m;
  __syncthreads();
  if (tid==0){
    float mm=sm[0];
    for (int i=1;i<16;i++) mm=fmaxf(mm,sm[i]);
    M[0]=mm;
  }
}

__global__ void k_p(const float* __restrict__ s, const float* __restrict__ M,
                    float* __restrict__ p){
  int i=blockIdx.x*256+threadIdx.x;
  if (i<N_NODES) p[i]=expf(s[i]-M[0]);
}

__global__ void k_denom(const int* __restrict__ mask, const float* __restrict__ p,
                        float* __restrict__ dn){
  __shared__ float sm[4];
  int i=blockIdx.x, tid=threadIdx.x;
  const int* row = mask + (size_t)i*N_NODES;
  float s=0.f;
  for (int j=tid;j<N_NODES;j+=256) s += row[j] ? p[j] : 0.f;
  #pragma unroll
  for (int o=32;o>0;o>>=1) s+=__shfl_down(s,o);
  if ((tid&63)==0) sm[tid>>6]=s;
  __syncthreads();
  if (tid==0) dn[i]=sm[0]+sm[1]+sm[2]+sm[3];
}

__global__ void k_gfin(const float* __restrict__ G, const float* __restrict__ dn,
                       float* __restrict__ g){
  __shared__ float sm[4];
  __shared__ float tot;
  int n=blockIdx.x, c=threadIdx.x;
  float gp = G[(size_t)n*HIDC+c] / dn[n];
  float v = gp*gp;
  #pragma unroll
  for (int o=32;o>0;o>>=1) v+=__shfl_down(v,o);
  if ((c&63)==0) sm[c>>6]=v;
  __syncthreads();
  if (c==0) tot = sm[0]+sm[1]+sm[2]+sm[3];
  __syncthreads();
  float nrm = sqrtf(tot);
  float x = gp/fmaxf(nrm,1e-12f);
  g[(size_t)n*HIDC+c]=1.f/(1.f+expf(-x));
}

// ---------------- discriminator ----------------
__global__ void k_disc(const float* __restrict__ z, const float* __restrict__ za,
                       const float* __restrict__ V, const float* __restrict__ Va,
                       const float* __restrict__ bbp, const float* __restrict__ biasp,
                       float* __restrict__ ret, float* __restrict__ ret_a){
  __shared__ float sm[16];
  int n=blockIdx.x, c=threadIdx.x;
  float ez = z[(size_t)n*HIDC+c], ea = za[(size_t)n*HIDC+c];
  float v  = V[(size_t)n*HIDC+c], va = Va[(size_t)n*HIDC+c];
  float p1=ez*v, p2=ea*v, p3=ea*va, p4=ez*va;
  #pragma unroll
  for (int o=32;o>0;o>>=1){
    p1+=__shfl_down(p1,o); p2+=__shfl_down(p2,o);
    p3+=__shfl_down(p3,o); p4+=__shfl_down(p4,o);
  }
  int lane=c&63, w=c>>6;
  if (lane==0){ sm[w]=p1; sm[4+w]=p2; sm[8+w]=p3; sm[12+w]=p4; }
  __syncthreads();
  if (c==0){
    float add = bbp[0]+biasp[0];
    ret[n*2+0]   = sm[0]+sm[1]+sm[2]+sm[3]   + add;
    ret[n*2+1]   = sm[4]+sm[5]+sm[6]+sm[7]   + add;
    ret_a[n*2+0] = sm[8]+sm[9]+sm[10]+sm[11] + add;
    ret_a[n*2+1] = sm[12]+sm[13]+sm[14]+sm[15] + add;
  }
}

extern "C" void kernel_launch(void* const* d_in, const int* in_sizes, int n_in,
                              void* d_out, int out_size, void* d_ws, size_t ws_size,
                              hipStream_t stream){
  (void)in_sizes; (void)n_in; (void)out_size; (void)ws_size;
  const float* feat   = (const float*)d_in[0];
  const float* feat_a = (const float*)d_in[1];
  const int*   ei     = (const int*)d_in[2];
  const float* ew     = (const float*)d_in[3];
  const int*   mask   = (const int*)d_in[4];
  const float* W1     = (const float*)d_in[5];
  const float* a_src1 = (const float*)d_in[6];
  const float* a_dst1 = (const float*)d_in[7];
  const float* b1     = (const float*)d_in[8];
  const float* W2     = (const float*)d_in[9];
  const float* a_src2 = (const float*)d_in[10];
  const float* a_dst2 = (const float*)d_in[11];
  const float* b2     = (const float*)d_in[12];
  const float* pw1    = (const float*)d_in[13];
  const float* pb1    = (const float*)d_in[14];
  const float* pw2    = (const float*)d_in[15];
  const float* pb2    = (const float*)d_in[16];
  const float* dw     = (const float*)d_in[17];
  const float* dbb    = (const float*)d_in[18];
  const float* dbias  = (const float*)d_in[19];

  float* out  = (float*)d_out;
  float* z    = out;
  float* hout = out + (size_t)N_NODES*HIDC;
  float* ret  = hout + (size_t)N_NODES*F_INF;
  float* ret_a= ret + (size_t)N_NODES*2;

  char* cur = (char*)d_ws;
  auto alloc = [&](size_t bytes)->void*{
    void* p = cur; cur += (bytes + 255) & ~(size_t)255; return p;
  };
  // R1: time-shared big region: featb -> feat_ab -> h2b -> maskb
  u16* R1   = (u16*)alloc((size_t)N_NODES*N_NODES*2);
  u16* W1T  = (u16*)alloc((size_t)HIDC*FPAD*2);
  u16* W2T  = (u16*)alloc((size_t)NPAD*HIDC*2);
  u16* zb   = (u16*)alloc((size_t)N_NODES*HIDC*2);
  u16* qT   = (u16*)alloc((size_t)HIDC*N_NODES*2);
  u16* gvb  = (u16*)alloc((size_t)N_NODES*HIDC*2);
  u16* dwb  = (u16*)alloc((size_t)HIDC*HIDC*2);
  float* h1  = (float*)alloc((size_t)N_NODES*HIDC*4);
  float* h1a = (float*)alloc((size_t)N_NODES*HIDC*4);
  float* za  = (float*)alloc((size_t)N_NODES*HIDC*4);
  float* G   = (float*)alloc((size_t)N_NODES*HIDC*4);
  float* gv  = (float*)alloc((size_t)N_NODES*HIDC*4);
  float* gva = (float*)alloc((size_t)N_NODES*HIDC*4);
  float* V   = (float*)alloc((size_t)N_NODES*HIDC*4);
  float* Va  = (float*)alloc((size_t)N_NODES*HIDC*4);
  float* ss1 = (float*)alloc(N_NODES*4*4);
  float* sd1 = (float*)alloc(N_NODES*4*4);
  float* ss2 = (float*)alloc(N_NODES*4);
  float* sd2 = (float*)alloc(N_NODES*4);
  float* scA = (float*)alloc(N_NODES*4);
  float* scB = (float*)alloc(N_NODES*4);
  float* pv  = (float*)alloc(N_NODES*4);
  float* dnv = (float*)alloc(N_NODES*4);
  float* Mb  = (float*)alloc(256);
  int* deg    = (int*)alloc(N_NODES*4);
  int* off    = (int*)alloc((N_NODES+64)*4);
  int* cursor = (int*)alloc(N_NODES*4);
  int* csrc   = (int*)alloc(NEDGE*4);
  float* csw  = (float*)alloc(NEDGE*4);

  // ---- CSR build ----
  hipMemsetAsync(deg, 0, N_NODES*sizeof(int), stream);
  hipMemsetAsync(cursor, 0, N_NODES*sizeof(int), stream);
  k_deg<<<NEDGE/256,256,0,stream>>>(ei+NEDGE, deg);
  k_scan<<<1,1024,0,stream>>>(deg, off);
  k_fill<<<NEDGE/256,256,0,stream>>>(ei, ew, off, cursor, csrc, csw);

  // ---- weight conversions ----
  k_trcvt<<<dim3(HIDC/32, FPAD/32),256,0,stream>>>(W1, W1T, F_INF, HIDC, FPAD, nullptr);
  k_trcvt<<<dim3(NPAD/32, HIDC/32),256,0,stream>>>(W2, W2T, HIDC, F_INF, HIDC, nullptr);

  // ---- branch 1 projection: h1 = feat @ W1 ----
  int nblk_cvt = (int)(((size_t)N_NODES*FPAD/4 + 255)/256);
  k_cvt<<<nblk_cvt,256,0,stream>>>(feat, R1, N_NODES, F_INF, FPAD);
  k_mgemm<false><<<dim3(HIDC/128, N_NODES/128),256,0,stream>>>(R1, W1T, h1, N_NODES, HIDC, FPAD, HIDC);
  k_scores1<<<N_NODES,256,0,stream>>>(h1, a_src1, a_dst1, ss1, sd1);
  k_gat1<<<N_NODES,256,0,stream>>>(h1, ss1, sd1, off, csrc, csw, b1, z);

  // ---- branch a projection (reuses R1) ----
  k_cvt<<<nblk_cvt,256,0,stream>>>(feat_a, R1, N_NODES, F_INF, FPAD);
  k_mgemm<false><<<dim3(HIDC/128, N_NODES/128),256,0,stream>>>(R1, W1T, h1a, N_NODES, HIDC, FPAD, HIDC);
  k_scores1<<<N_NODES,256,0,stream>>>(h1a, a_src1, a_dst1, ss1, sd1);
  k_gat1<<<N_NODES,256,0,stream>>>(h1a, ss1, sd1, off, csrc, csw, b1, za);

  // ---- GAT2: h2 = z @ W2 (bf16 C into R1), then aggregate ----
  int nblk_z = (int)(((size_t)N_NODES*HIDC/4 + 255)/256);
  k_cvt<<<nblk_z,256,0,stream>>>(z, zb, N_NODES, HIDC, HIDC);
  k_mgemm<true><<<dim3(NPAD/128, N_NODES/128),256,0,stream>>>(zb, W2T, R1, N_NODES, NPAD, HIDC, NPAD);
  k_scores2<<<N_NODES,256,0,stream>>>(R1, a_src2, a_dst2, ss2, sd2);
  k_gat2<<<N_NODES,256,0,stream>>>(R1, ss2, sd2, off, csrc, csw, b2, hout);

  // ---- pooling scores ----
  k_pool<<<N_NODES,128,0,stream>>>(z,  pw1, pb1, pw2, pb2, scA);
  k_pool<<<N_NODES,128,0,stream>>>(za, pw1, pb1, pw2, pb2, scB);

  // ---- mask to bf16 (reuses R1) ----
  k_cvt_mask<<<(int)((size_t)N_NODES*N_NODES/4/256),256,0,stream>>>(mask, R1);

  // ---- branch 1 pooling ----
  k_maxred<<<1,1024,0,stream>>>(scA, Mb);
  k_p<<<N_NODES/256,256,0,stream>>>(scA, Mb, pv);
  k_trcvt<<<dim3(HIDC/32, N_NODES/32),256,0,stream>>>(z, qT, N_NODES, HIDC, N_NODES, pv);
  k_denom<<<N_NODES,256,0,stream>>>(mask, pv, dnv);
  k_mgemm<false><<<dim3(HIDC/128, N_NODES/128),256,0,stream>>>(R1, qT, G, N_NODES, HIDC, N_NODES, HIDC);
  k_gfin<<<N_NODES,256,0,stream>>>(G, dnv, gv);

  // ---- branch a pooling ----
  k_maxred<<<1,1024,0,stream>>>(scB, Mb);
  k_p<<<N_NODES/256,256,0,stream>>>(scB, Mb, pv);
  k_trcvt<<<dim3(HIDC/32, N_NODES/32),256,0,stream>>>(za, qT, N_NODES, HIDC, N_NODES, pv);
  k_denom<<<N_NODES,256,0,stream>>>(mask, pv, dnv);
  k_mgemm<false><<<dim3(HIDC/128, N_NODES/128),256,0,stream>>>(R1, qT, G, N_NODES, HIDC, N_NODES, HIDC);
  k_gfin<<<N_NODES,256,0,stream>>>(G, dnv, gva);

  // ---- discriminator ----
  k_cvt<<<HIDC*HIDC/4/256,256,0,stream>>>(dw, dwb, HIDC, HIDC, HIDC);
  k_cvt<<<nblk_z,256,0,stream>>>(gv, gvb, N_NODES, HIDC, HIDC);
  k_mgemm<false><<<dim3(HIDC/128, N_NODES/128),256,0,stream>>>(gvb, dwb, V, N_NODES, HIDC, HIDC, HIDC);
  k_cvt<<<nblk_z,256,0,stream>>>(gva, gvb, N_NODES, HIDC, HIDC);
  k_mgemm<false><<<dim3(HIDC/128, N_NODES/128),256,0,stream>>>(gvb, dwb, Va, N_NODES, HIDC, HIDC, HIDC);
  k_disc<<<N_NODES,256,0,stream>>>(z, za, V, Va, dbb, dbias, ret, ret_a);
}

// Round 3
// 513.844 us; speedup vs baseline: 4.7108x; 1.3068x over previous
//
#include <hip/hip_runtime.h>
#include <cstdint>
#include <cstddef>

#define N_NODES 4096
#define F_INF   3000
#define FPAD    3008
#define NPAD    3072
#define HIDC    256
#define NEDGE   65536
#define POOLH   128

typedef unsigned short u16;
typedef __attribute__((ext_vector_type(8))) short bf16x8;
typedef __attribute__((ext_vector_type(8))) unsigned short us8;
typedef __attribute__((ext_vector_type(4))) float f32x4;

__device__ inline float lrelu(float x){ return x > 0.f ? x : 0.2f*x; }
__device__ inline u16 f2b(float f){
  uint32_t x = __builtin_bit_cast(uint32_t, f);
  uint32_t r = (x + 0x7fffu + ((x >> 16) & 1u)) >> 16;
  return (u16)r;
}
__device__ inline float b2f(u16 u){
  uint32_t x = ((uint32_t)u) << 16;
  return __builtin_bit_cast(float, x);
}
// XOR swizzle for [row][64 bf16] tiles (128B rows): spreads the 16B slot
// across 8 slots per 8-row stripe -> conflict-free b128 read/write.
__device__ __forceinline__ int swz(int row, int cb){
  return row*128 + (cb ^ ((row & 7) << 4));
}

// ---------------- CSR build ----------------
__global__ void k_deg(const int* __restrict__ dst, int* __restrict__ deg){
  int e = blockIdx.x*256 + threadIdx.x;
  if (e < NEDGE) atomicAdd(&deg[dst[e]], 1);
}

__global__ void k_scan(const int* __restrict__ deg, int* __restrict__ off){
  __shared__ int sm[1024];
  int tid = threadIdx.x;
  int v0=deg[tid*4], v1=deg[tid*4+1], v2=deg[tid*4+2], v3=deg[tid*4+3];
  int s = v0+v1+v2+v3;
  sm[tid]=s; __syncthreads();
  for (int d=1; d<1024; d<<=1){
    int t = (tid>=d)? sm[tid-d] : 0;
    __syncthreads();
    sm[tid] += t;
    __syncthreads();
  }
  int run = sm[tid]-s;
  off[tid*4+0]=run; run+=v0;
  off[tid*4+1]=run; run+=v1;
  off[tid*4+2]=run; run+=v2;
  off[tid*4+3]=run; run+=v3;
  if (tid==1023) off[N_NODES]=run;
}

__global__ void k_fill(const int* __restrict__ ei, const float* __restrict__ ew,
                       const int* __restrict__ off, int* __restrict__ cursor,
                       int* __restrict__ csr_src, float* __restrict__ csr_w){
  int e = blockIdx.x*256+threadIdx.x;
  if (e >= NEDGE) return;
  int d = ei[NEDGE + e];
  int slot = off[d] + atomicAdd(&cursor[d],1);
  csr_src[slot] = ei[e];
  csr_w[slot] = ew[e];
}

// ---------------- conversions ----------------
__global__ void k_cvt(const float* __restrict__ in, u16* __restrict__ out,
                      int R, int Cin, int Cout){
  size_t i = ((size_t)blockIdx.x*256 + threadIdx.x)*4;
  if (i >= (size_t)R*Cout) return;
  int r = (int)(i / Cout), c = (int)(i % Cout);
  ushort4 o;
  if (c + 3 < Cin){
    float4 v = *(const float4*)(in + (size_t)r*Cin + c);
    o.x=f2b(v.x); o.y=f2b(v.y); o.z=f2b(v.z); o.w=f2b(v.w);
  } else {
    float vs[4];
    #pragma unroll
    for (int j=0;j<4;j++) vs[j] = (c+j<Cin)? in[(size_t)r*Cin+c+j] : 0.f;
    o.x=f2b(vs[0]); o.y=f2b(vs[1]); o.z=f2b(vs[2]); o.w=f2b(vs[3]);
  }
  *(ushort4*)(out+i) = o;
}

// out[c][r] = in[r][c] * (scale?scale[r]:1), bf16, zero-pad outside [R][C].
__global__ void k_trcvt(const float* __restrict__ in, u16* __restrict__ out,
                        int R, int C, int OCols, const float* __restrict__ scale){
  __shared__ float t[32][33];
  int c0 = blockIdx.x*32, r0 = blockIdx.y*32;
  int tx = threadIdx.x & 31, ty = threadIdx.x >> 5;
  #pragma unroll
  for (int i=0;i<4;i++){
    int r = r0 + ty + i*8, c = c0 + tx;
    float v = (r<R && c<C) ? in[(size_t)r*C + c] : 0.f;
    if (scale && r<R) v *= scale[r];
    t[ty+i*8][tx] = v;
  }
  __syncthreads();
  #pragma unroll
  for (int i=0;i<4;i++){
    int c = c0 + ty + i*8, r = r0 + tx;
    out[(size_t)c*OCols + r] = f2b(t[tx][ty+i*8]);
  }
}

// ------- MFMA GEMM, reg-staged A with conversion, swizzled LDS -------
// C[M,N] = A[M,K] @ B^T where B given [N][ldb] bf16 (zero-padded to >= ceil64(K)).
// A: ATYPE 0 = f32 (two stacked pointers, split at srow), 1 = int32 mask (0/1).
// grid (N/BN, M/BM, SPLITK); block z handles K rows [z*kcount, min(K,(z+1)*kcount)),
// writing slab z of C (f32 only when SPLITK>1).
template<int BM, int BN, int ATYPE, int CTYPE>
__global__ __launch_bounds__(256) void k_mg(
    const void* __restrict__ A0v, const void* __restrict__ A1v, int srow,
    const u16* __restrict__ B, void* __restrict__ Cv,
    int M, int Nn, int K, int lda, int ldb, int ldc, int kcount){
  constexpr int WM = BM/2, WN = BN/2, MR = WM/16, NR = WN/16;
  __shared__ __align__(16) u16 sA[BM*64];
  __shared__ __align__(16) u16 sB[BN*64];
  const int tid = threadIdx.x;
  const int bm = blockIdx.y*BM, bn = blockIdx.x*BN;
  const int lane = tid & 63, w = tid >> 6;
  const int wr = w >> 1, wc = w & 1;
  f32x4 acc[MR][NR] = {};

  const int kbeg = blockIdx.z * kcount;
  const int kend = min(K, kbeg + kcount);

  for (int kk = kbeg; kk < kend; kk += 64){
    const int rem = kend - kk;   // remaining valid cols this step (>=1)
    // ---- stage A (convert to bf16, swizzled ds_write_b128) ----
    #pragma unroll
    for (int p = 0; p < BM/32; p++){
      int idx = (p*256 + tid)*8;
      int row = idx >> 6, col = idx & 63;
      int grow = bm + row;
      us8 o;
      if (ATYPE == 0){
        const float* Ar = (grow < srow) ? ((const float*)A0v + (size_t)grow*lda + kk)
                                        : ((const float*)A1v + (size_t)(grow-srow)*lda + kk);
        if (col + 8 <= rem){
          float4 v0 = *(const float4*)(Ar + col);
          float4 v1 = *(const float4*)(Ar + col + 4);
          o[0]=f2b(v0.x); o[1]=f2b(v0.y); o[2]=f2b(v0.z); o[3]=f2b(v0.w);
          o[4]=f2b(v1.x); o[5]=f2b(v1.y); o[6]=f2b(v1.z); o[7]=f2b(v1.w);
        } else {
          #pragma unroll
          for (int j=0;j<8;j++) o[j] = (col+j < rem) ? f2b(Ar[col+j]) : (u16)0;
        }
      } else {
        const int* Ar = (const int*)A0v + (size_t)grow*lda + kk;
        if (col + 8 <= rem){
          int4 v0 = *(const int4*)(Ar + col);
          int4 v1 = *(const int4*)(Ar + col + 4);
          o[0]=v0.x?0x3f80:0; o[1]=v0.y?0x3f80:0; o[2]=v0.z?0x3f80:0; o[3]=v0.w?0x3f80:0;
          o[4]=v1.x?0x3f80:0; o[5]=v1.y?0x3f80:0; o[6]=v1.z?0x3f80:0; o[7]=v1.w?0x3f80:0;
        } else {
          #pragma unroll
          for (int j=0;j<8;j++) o[j] = (col+j < rem && Ar[col+j]) ? (u16)0x3f80 : (u16)0;
        }
      }
      *(us8*)((char*)sA + swz(row, col*2)) = o;
    }
    // ---- stage B (already bf16, padded) ----
    #pragma unroll
    for (int p = 0; p < BN/32; p++){
      int idx = (p*256 + tid)*8;
      int row = idx >> 6, col = idx & 63;
      us8 o = *(const us8*)(B + (size_t)(bn+row)*ldb + kk + col);
      *(us8*)((char*)sB + swz(row, col*2)) = o;
    }
    __syncthreads();
    // ---- MFMA ----
    #pragma unroll
    for (int ks = 0; ks < 2; ks++){
      bf16x8 af[MR], bfr[NR];
      #pragma unroll
      for (int m=0;m<MR;m++)
        af[m] = *(const bf16x8*)((char*)sA + swz(wr*WM + m*16 + (lane&15), ks*64 + (lane>>4)*16));
      #pragma unroll
      for (int n=0;n<NR;n++)
        bfr[n] = *(const bf16x8*)((char*)sB + swz(wc*WN + n*16 + (lane&15), ks*64 + (lane>>4)*16));
      #pragma unroll
      for (int m=0;m<MR;m++)
        #pragma unroll
        for (int n=0;n<NR;n++)
          acc[m][n] = __builtin_amdgcn_mfma_f32_16x16x32_bf16(af[m], bfr[n], acc[m][n], 0,0,0);
    }
    __syncthreads();
  }

  const size_t slab = (size_t)blockIdx.z * (size_t)M * ldc;
  const int rbase = bm + wr*WM + ((lane>>4)<<2);
  const int cbase = bn + wc*WN + (lane&15);
  if (CTYPE == 1){
    u16* C = (u16*)Cv + slab;
    #pragma unroll
    for (int m=0;m<MR;m++)
      #pragma unroll
      for (int n=0;n<NR;n++)
        #pragma unroll
        for (int j=0;j<4;j++)
          C[(size_t)(rbase + m*16 + j)*ldc + cbase + n*16] = f2b(acc[m][n][j]);
  } else {
    float* C = (float*)Cv + slab;
    #pragma unroll
    for (int m=0;m<MR;m++)
      #pragma unroll
      for (int n=0;n<NR;n++)
        #pragma unroll
        for (int j=0;j<4;j++)
          C[(size_t)(rbase + m*16 + j)*ldc + cbase + n*16] = acc[m][n][j];
  }
}

// ---------------- GAT layer 1 (4 heads x 64 ch) ----------------
__global__ void k_scores1(const float* __restrict__ h1, const float* __restrict__ a_src,
                          const float* __restrict__ a_dst, float* __restrict__ s_src,
                          float* __restrict__ s_dst){
  int n = blockIdx.x, c = threadIdx.x;
  float v = h1[(size_t)n*HIDC + c];
  float vs = v * a_src[c];
  float vd = v * a_dst[c];
  #pragma unroll
  for (int o=32;o>0;o>>=1){ vs += __shfl_down(vs,o); vd += __shfl_down(vd,o); }
  if ((c&63)==0){ int h=c>>6; s_src[n*4+h]=vs; s_dst[n*4+h]=vd; }
}

__global__ void k_gat1(const float* __restrict__ h1, const float* __restrict__ s_src,
                       const float* __restrict__ s_dst, const int* __restrict__ off,
                       const int* __restrict__ csr_src, const float* __restrict__ csr_w,
                       const float* __restrict__ b1, float* __restrict__ z){
  int n = blockIdx.x, c = threadIdx.x, h = c>>6;
  int o0 = off[n], o1 = off[n+1];
  float sd = s_dst[n*4+h];
  float m = -1e30f;
  for (int t=o0;t<o1;t++){
    int s = csr_src[t];
    m = fmaxf(m, lrelu(s_src[s*4+h]+sd));
  }
  float denom=0.f, acc=0.f;
  for (int t=o0;t<o1;t++){
    int s = csr_src[t];
    float wv = expf(lrelu(s_src[s*4+h]+sd)-m)*csr_w[t];
    denom += wv;
    acc += wv * h1[(size_t)s*HIDC + c];
  }
  float res = acc/(denom+1e-16f) + b1[c];
  z[(size_t)n*HIDC+c] = fmaxf(res, 0.f);
}

// ---------------- GAT layer 2 (1 head x 3000 ch, h2 bf16 ld=NPAD) ----------------
__global__ void k_scores2(const u16* __restrict__ h2, const float* __restrict__ a_src,
                          const float* __restrict__ a_dst, float* __restrict__ s_src,
                          float* __restrict__ s_dst){
  __shared__ float sm[8];
  int n = blockIdx.x, tid = threadIdx.x;
  const u16* row = h2 + (size_t)n*NPAD;
  float vs=0.f, vd=0.f;
  for (int c = tid*8; c < F_INF; c += 2048){
    ushort4 u0 = *(const ushort4*)(row + c);
    ushort4 u1 = *(const ushort4*)(row + c + 4);
    float f0=b2f(u0.x), f1=b2f(u0.y), f2=b2f(u0.z), f3=b2f(u0.w);
    float f4=b2f(u1.x), f5=b2f(u1.y), f6=b2f(u1.z), f7=b2f(u1.w);
    vs += f0*a_src[c]+f1*a_src[c+1]+f2*a_src[c+2]+f3*a_src[c+3]
        + f4*a_src[c+4]+f5*a_src[c+5]+f6*a_src[c+6]+f7*a_src[c+7];
    vd += f0*a_dst[c]+f1*a_dst[c+1]+f2*a_dst[c+2]+f3*a_dst[c+3]
        + f4*a_dst[c+4]+f5*a_dst[c+5]+f6*a_dst[c+6]+f7*a_dst[c+7];
  }
  #pragma unroll
  for (int o=32;o>0;o>>=1){ vs+=__shfl_down(vs,o); vd+=__shfl_down(vd,o); }
  int lane=tid&63, w=tid>>6;
  if (lane==0){ sm[w]=vs; sm[4+w]=vd; }
  __syncthreads();
  if (tid==0) s_src[n]=sm[0]+sm[1]+sm[2]+sm[3];
  if (tid==1) s_dst[n]=sm[4]+sm[5]+sm[6]+sm[7];
}

__global__ void k_gat2(const u16* __restrict__ h2, const float* __restrict__ s_src,
                       const float* __restrict__ s_dst, const int* __restrict__ off,
                       const int* __restrict__ csr_src, const float* __restrict__ csr_w,
                       const float* __restrict__ b2, float* __restrict__ hout){
  int n = blockIdx.x, tid = threadIdx.x;
  int o0=off[n], o1=off[n+1];
  float sd = s_dst[n];
  float m=-1e30f;
  for (int t=o0;t<o1;t++) m = fmaxf(m, lrelu(s_src[csr_src[t]]+sd));
  float denom=0.f;
  float acc[12];
  #pragma unroll
  for (int k=0;k<12;k++) acc[k]=0.f;
  int c0 = tid*12;
  bool act = c0 < F_INF;
  for (int t=o0;t<o1;t++){
    int s=csr_src[t];
    float wv = expf(lrelu(s_src[s]+sd)-m)*csr_w[t];
    denom += wv;
    if (act){
      const ushort4* r4 = (const ushort4*)(h2 + (size_t)s*NPAD + c0);
      #pragma unroll
      for (int v=0;v<3;v++){
        ushort4 u = r4[v];
        acc[v*4+0] += wv*b2f(u.x);
        acc[v*4+1] += wv*b2f(u.y);
        acc[v*4+2] += wv*b2f(u.z);
        acc[v*4+3] += wv*b2f(u.w);
      }
    }
  }
  float inv = 1.f/(denom+1e-16f);
  if (act){
    #pragma unroll
    for (int k=0;k<12;k++)
      hout[(size_t)n*F_INF + c0 + k] = acc[k]*inv + b2[c0+k];
  }
}

// ---------------- attention pooling ----------------
__global__ void k_pool(const float* __restrict__ emb, const float* __restrict__ w1,
                       const float* __restrict__ b1, const float* __restrict__ w2,
                       const float* __restrict__ b2, float* __restrict__ scores){
  __shared__ float ze[HIDC];
  __shared__ float red[POOLH];
  int n = blockIdx.x, t = threadIdx.x;
  ze[t]     = emb[(size_t)n*HIDC + t];
  ze[t+128] = emb[(size_t)n*HIDC + t + 128];
  __syncthreads();
  float acc = b1[t];
  for (int d=0; d<HIDC; d++) acc += ze[d]*w1[d*POOLH + t];
  float hidden = fmaxf(acc, 0.f);
  red[t] = hidden * w2[t];
  __syncthreads();
  for (int s=64; s>0; s>>=1){
    if (t < s) red[t] += red[t+s];
    __syncthreads();
  }
  if (t==0) scores[n] = red[0] + b2[0];
}

__global__ void k_maxred(const float* __restrict__ s, float* __restrict__ M){
  __shared__ float sm[16];
  int tid=threadIdx.x;
  float m=-1e30f;
  for (int i=tid;i<N_NODES;i+=1024) m=fmaxf(m,s[i]);
  #pragma unroll
  for (int o=32;o>0;o>>=1) m=fmaxf(m,__shfl_down(m,o));
  if ((tid&63)==0) sm[tid>>6]=m;
  __syncthreads();
  if (tid==0){
    float mm=sm[0];
    for (int i=1;i<16;i++) mm=fmaxf(mm,sm[i]);
    M[0]=mm;
  }
}

__global__ void k_p(const float* __restrict__ s, const float* __restrict__ M,
                    float* __restrict__ p){
  int i=blockIdx.x*256+threadIdx.x;
  if (i<N_NODES) p[i]=expf(s[i]-M[0]);
}

// one pass over mask computes both branch denominators
__global__ void k_denom2(const int* __restrict__ mask, const float* __restrict__ pA,
                         const float* __restrict__ pB, float* __restrict__ dnA,
                         float* __restrict__ dnB){
  __shared__ float sm[8];
  int i=blockIdx.x, tid=threadIdx.x;
  const int* row = mask + (size_t)i*N_NODES;
  float sa=0.f, sb=0.f;
  for (int j0 = tid*4; j0 < N_NODES; j0 += 1024){
    int4 mv = *(const int4*)(row + j0);
    float4 pa = *(const float4*)(pA + j0);
    float4 pb = *(const float4*)(pB + j0);
    if (mv.x){ sa += pa.x; sb += pb.x; }
    if (mv.y){ sa += pa.y; sb += pb.y; }
    if (mv.z){ sa += pa.z; sb += pb.z; }
    if (mv.w){ sa += pa.w; sb += pb.w; }
  }
  #pragma unroll
  for (int o=32;o>0;o>>=1){ sa+=__shfl_down(sa,o); sb+=__shfl_down(sb,o); }
  int lane=tid&63, w=tid>>6;
  if (lane==0){ sm[w]=sa; sm[4+w]=sb; }
  __syncthreads();
  if (tid==0) dnA[i]=sm[0]+sm[1]+sm[2]+sm[3];
  if (tid==1) dnB[i]=sm[4]+sm[5]+sm[6]+sm[7];
}

// sums the two split-K slabs of G, normalizes, sigmoids
__global__ void k_gfin(const float* __restrict__ G0, const float* __restrict__ G1,
                       const float* __restrict__ dn, float* __restrict__ g, int co){
  __shared__ float sm[4];
  __shared__ float tot;
  int n=blockIdx.x, c=threadIdx.x;
  size_t idx = (size_t)n*512 + co + c;
  float gp = (G0[idx] + G1[idx]) / dn[n];
  float v = gp*gp;
  #pragma unroll
  for (int o=32;o>0;o>>=1) v+=__shfl_down(v,o);
  if ((c&63)==0) sm[c>>6]=v;
  __syncthreads();
  if (c==0) tot = sm[0]+sm[1]+sm[2]+sm[3];
  __syncthreads();
  float nrm = sqrtf(tot);
  float x = gp/fmaxf(nrm,1e-12f);
  g[(size_t)n*HIDC+c]=1.f/(1.f+expf(-x));
}

// ---------------- discriminator ----------------
__global__ void k_disc(const float* __restrict__ z, const float* __restrict__ za,
                       const float* __restrict__ V, const float* __restrict__ Va,
                       const float* __restrict__ bbp, const float* __restrict__ biasp,
                       float* __restrict__ ret, float* __restrict__ ret_a){
  __shared__ float sm[16];
  int n=blockIdx.x, c=threadIdx.x;
  float ez = z[(size_t)n*HIDC+c], ea = za[(size_t)n*HIDC+c];
  float v  = V[(size_t)n*HIDC+c], va = Va[(size_t)n*HIDC+c];
  float p1=ez*v, p2=ea*v, p3=ea*va, p4=ez*va;
  #pragma unroll
  for (int o=32;o>0;o>>=1){
    p1+=__shfl_down(p1,o); p2+=__shfl_down(p2,o);
    p3+=__shfl_down(p3,o); p4+=__shfl_down(p4,o);
  }
  int lane=c&63, w=c>>6;
  if (lane==0){ sm[w]=p1; sm[4+w]=p2; sm[8+w]=p3; sm[12+w]=p4; }
  __syncthreads();
  if (c==0){
    float add = bbp[0]+biasp[0];
    ret[n*2+0]   = sm[0]+sm[1]+sm[2]+sm[3]   + add;
    ret[n*2+1]   = sm[4]+sm[5]+sm[6]+sm[7]   + add;
    ret_a[n*2+0] = sm[8]+sm[9]+sm[10]+sm[11] + add;
    ret_a[n*2+1] = sm[12]+sm[13]+sm[14]+sm[15] + add;
  }
}

extern "C" void kernel_launch(void* const* d_in, const int* in_sizes, int n_in,
                              void* d_out, int out_size, void* d_ws, size_t ws_size,
                              hipStream_t stream){
  (void)in_sizes; (void)n_in; (void)out_size; (void)ws_size;
  const float* feat   = (const float*)d_in[0];
  const float* feat_a = (const float*)d_in[1];
  const int*   ei     = (const int*)d_in[2];
  const float* ew     = (const float*)d_in[3];
  const int*   mask   = (const int*)d_in[4];
  const float* W1     = (const float*)d_in[5];
  const float* a_src1 = (const float*)d_in[6];
  const float* a_dst1 = (const float*)d_in[7];
  const float* b1     = (const float*)d_in[8];
  const float* W2     = (const float*)d_in[9];
  const float* a_src2 = (const float*)d_in[10];
  const float* a_dst2 = (const float*)d_in[11];
  const float* b2     = (const float*)d_in[12];
  const float* pw1    = (const float*)d_in[13];
  const float* pb1    = (const float*)d_in[14];
  const float* pw2    = (const float*)d_in[15];
  const float* pb2    = (const float*)d_in[16];
  const float* dw     = (const float*)d_in[17];
  const float* dbb    = (const float*)d_in[18];
  const float* dbias  = (const float*)d_in[19];

  float* out  = (float*)d_out;
  float* z    = out;
  float* hout = out + (size_t)N_NODES*HIDC;
  float* ret  = hout + (size_t)N_NODES*F_INF;
  float* ret_a= ret + (size_t)N_NODES*2;

  char* cur = (char*)d_ws;
  auto alloc = [&](size_t bytes)->void*{
    void* p = cur; cur += (bytes + 255) & ~(size_t)255; return p;
  };
  u16* h2b  = (u16*)alloc((size_t)N_NODES*NPAD*2);      // 24 MB
  u16* W1T  = (u16*)alloc((size_t)HIDC*FPAD*2);
  u16* W2T  = (u16*)alloc((size_t)NPAD*HIDC*2);
  u16* qT   = (u16*)alloc((size_t)512*N_NODES*2);       // [qT | qaT]
  u16* dwb  = (u16*)alloc((size_t)HIDC*HIDC*2);
  float* h1st = (float*)alloc((size_t)2*N_NODES*HIDC*4); // stacked h1;h1a
  float* za   = (float*)alloc((size_t)N_NODES*HIDC*4);
  float* G    = (float*)alloc((size_t)2*N_NODES*512*4);  // 2 split-K slabs
  float* Vst  = (float*)alloc((size_t)2*N_NODES*HIDC*4); // stacked V;Va
  float* gv   = (float*)alloc((size_t)N_NODES*HIDC*4);
  float* gva  = (float*)alloc((size_t)N_NODES*HIDC*4);
  float* ss1 = (float*)alloc(N_NODES*4*4);
  float* sd1 = (float*)alloc(N_NODES*4*4);
  float* ss2 = (float*)alloc(N_NODES*4);
  float* sd2 = (float*)alloc(N_NODES*4);
  float* scA = (float*)alloc(N_NODES*4);
  float* scB = (float*)alloc(N_NODES*4);
  float* pvA = (float*)alloc(N_NODES*4);
  float* pvB = (float*)alloc(N_NODES*4);
  float* dnA = (float*)alloc(N_NODES*4);
  float* dnB = (float*)alloc(N_NODES*4);
  float* MbA = (float*)alloc(256);
  float* MbB = (float*)alloc(256);
  int* deg    = (int*)alloc(N_NODES*4);
  int* off    = (int*)alloc((N_NODES+64)*4);
  int* cursor = (int*)alloc(N_NODES*4);
  int* csrc   = (int*)alloc(NEDGE*4);
  float* csw  = (float*)alloc(NEDGE*4);

  float* h1  = h1st;
  float* h1a = h1st + (size_t)N_NODES*HIDC;
  float* V   = Vst;
  float* Va  = Vst + (size_t)N_NODES*HIDC;
  float* G1s = G + (size_t)N_NODES*512;

  // ---- CSR build ----
  hipMemsetAsync(deg, 0, N_NODES*sizeof(int), stream);
  hipMemsetAsync(cursor, 0, N_NODES*sizeof(int), stream);
  k_deg<<<NEDGE/256,256,0,stream>>>(ei+NEDGE, deg);
  k_scan<<<1,1024,0,stream>>>(deg, off);
  k_fill<<<NEDGE/256,256,0,stream>>>(ei, ew, off, cursor, csrc, csw);

  // ---- weight conversions ----
  k_trcvt<<<dim3(HIDC/32, FPAD/32),256,0,stream>>>(W1, W1T, F_INF, HIDC, FPAD, nullptr);
  k_trcvt<<<dim3(NPAD/32, HIDC/32),256,0,stream>>>(W2, W2T, HIDC, F_INF, HIDC, nullptr);
  k_cvt<<<HIDC*HIDC/4/256,256,0,stream>>>(dw, dwb, HIDC, HIDC, HIDC);

  // ---- stacked projection: [h1;h1a] = [feat;feat_a] @ W1 ----
  k_mg<128,64,0,0><<<dim3(HIDC/64, 2*N_NODES/128, 1),256,0,stream>>>(
      feat, feat_a, N_NODES, W1T, h1st, 2*N_NODES, HIDC, F_INF, F_INF, FPAD, HIDC, F_INF);

  // ---- GAT1 both branches ----
  k_scores1<<<N_NODES,256,0,stream>>>(h1, a_src1, a_dst1, ss1, sd1);
  k_gat1<<<N_NODES,256,0,stream>>>(h1, ss1, sd1, off, csrc, csw, b1, z);
  k_scores1<<<N_NODES,256,0,stream>>>(h1a, a_src1, a_dst1, ss1, sd1);
  k_gat1<<<N_NODES,256,0,stream>>>(h1a, ss1, sd1, off, csrc, csw, b1, za);

  // ---- GAT2: h2 = z @ W2 (bf16, direct f32 A), then aggregate ----
  k_mg<128,128,0,1><<<dim3(NPAD/128, N_NODES/128, 1),256,0,stream>>>(
      z, z, N_NODES, W2T, h2b, N_NODES, NPAD, HIDC, HIDC, HIDC, NPAD, HIDC);
  k_scores2<<<N_NODES,256,0,stream>>>(h2b, a_src2, a_dst2, ss2, sd2);
  k_gat2<<<N_NODES,256,0,stream>>>(h2b, ss2, sd2, off, csrc, csw, b2, hout);

  // ---- pooling scores + softmax numerators ----
  k_pool<<<N_NODES,128,0,stream>>>(z,  pw1, pb1, pw2, pb2, scA);
  k_pool<<<N_NODES,128,0,stream>>>(za, pw1, pb1, pw2, pb2, scB);
  k_maxred<<<1,1024,0,stream>>>(scA, MbA);
  k_maxred<<<1,1024,0,stream>>>(scB, MbB);
  k_p<<<N_NODES/256,256,0,stream>>>(scA, MbA, pvA);
  k_p<<<N_NODES/256,256,0,stream>>>(scB, MbB, pvB);
  k_trcvt<<<dim3(HIDC/32, N_NODES/32),256,0,stream>>>(z,  qT, N_NODES, HIDC, N_NODES, pvA);
  k_trcvt<<<dim3(HIDC/32, N_NODES/32),256,0,stream>>>(za, qT + (size_t)HIDC*N_NODES, N_NODES, HIDC, N_NODES, pvB);
  k_denom2<<<N_NODES,256,0,stream>>>(mask, pvA, pvB, dnA, dnB);

  // ---- masked-softmax GEMM: G = Mask @ [q | qa], split-K=2 ----
  k_mg<128,128,1,0><<<dim3(512/128, N_NODES/128, 2),256,0,stream>>>(
      mask, mask, 2*N_NODES, qT, G, N_NODES, 512, N_NODES, N_NODES, N_NODES, 512, N_NODES/2);
  k_gfin<<<N_NODES,256,0,stream>>>(G, G1s, dnA, gv, 0);
  k_gfin<<<N_NODES,256,0,stream>>>(G, G1s, dnB, gva, HIDC);

  // ---- discriminator: [V;Va] = [gv;gva] @ dw^T ----
  k_mg<128,64,0,0><<<dim3(HIDC/64, 2*N_NODES/128, 1),256,0,stream>>>(
      gv, gva, N_NODES, dwb, Vst, 2*N_NODES, HIDC, HIDC, HIDC, HIDC, HIDC, HIDC);
  k_disc<<<N_NODES,256,0,stream>>>(z, za, V, Va, dbb, dbias, ret, ret_a);
}

// Round 4
// 393.173 us; speedup vs baseline: 6.1567x; 1.3069x over previous
//
#include <hip/hip_runtime.h>
#include <cstdint>
#include <cstddef>

#define N_NODES 4096
#define F_INF   3000
#define FPAD    3008
#define NPAD    3072
#define HIDC    256
#define NEDGE   65536
#define POOLH   128
#define GCOLS   576   // 256 (branch1) + 256 (branchA) + dnA + dnB + pad

typedef unsigned short u16;
typedef __attribute__((ext_vector_type(8))) short bf16x8;
typedef __attribute__((ext_vector_type(8))) unsigned short us8;
typedef __attribute__((ext_vector_type(4))) float f32x4;

__device__ inline float lrelu(float x){ return x > 0.f ? x : 0.2f*x; }
__device__ inline u16 f2b(float f){
  uint32_t x = __builtin_bit_cast(uint32_t, f);
  uint32_t r = (x + 0x7fffu + ((x >> 16) & 1u)) >> 16;
  return (u16)r;
}
__device__ inline float b2f(u16 u){
  uint32_t x = ((uint32_t)u) << 16;
  return __builtin_bit_cast(float, x);
}
// XOR swizzle for [row][64 bf16] tiles (128B rows): conflict-free b128 r/w.
__device__ __forceinline__ int swz(int row, int cb){
  return row*128 + (cb ^ ((row & 7) << 4));
}

// ---------------- CSR build ----------------
__global__ void k_deg(const int* __restrict__ dst, int* __restrict__ deg){
  int e = blockIdx.x*256 + threadIdx.x;
  if (e < NEDGE) atomicAdd(&deg[dst[e]], 1);
}

__global__ void k_scan(const int* __restrict__ deg, int* __restrict__ off){
  __shared__ int sm[1024];
  int tid = threadIdx.x;
  int v0=deg[tid*4], v1=deg[tid*4+1], v2=deg[tid*4+2], v3=deg[tid*4+3];
  int s = v0+v1+v2+v3;
  sm[tid]=s; __syncthreads();
  for (int d=1; d<1024; d<<=1){
    int t = (tid>=d)? sm[tid-d] : 0;
    __syncthreads();
    sm[tid] += t;
    __syncthreads();
  }
  int run = sm[tid]-s;
  off[tid*4+0]=run; run+=v0;
  off[tid*4+1]=run; run+=v1;
  off[tid*4+2]=run; run+=v2;
  off[tid*4+3]=run; run+=v3;
  if (tid==1023) off[N_NODES]=run;
}

__global__ void k_fill(const int* __restrict__ ei, const float* __restrict__ ew,
                       const int* __restrict__ off, int* __restrict__ cursor,
                       int* __restrict__ csr_src, float* __restrict__ csr_w){
  int e = blockIdx.x*256+threadIdx.x;
  if (e >= NEDGE) return;
  int d = ei[NEDGE + e];
  int slot = off[d] + atomicAdd(&cursor[d],1);
  csr_src[slot] = ei[e];
  csr_w[slot] = ew[e];
}

// ---------------- conversions ----------------
__global__ void k_cvt(const float* __restrict__ in, u16* __restrict__ out,
                      int R, int Cin, int Cout){
  size_t i = ((size_t)blockIdx.x*256 + threadIdx.x)*4;
  if (i >= (size_t)R*Cout) return;
  int r = (int)(i / Cout), c = (int)(i % Cout);
  ushort4 o;
  if (c + 3 < Cin){
    float4 v = *(const float4*)(in + (size_t)r*Cin + c);
    o.x=f2b(v.x); o.y=f2b(v.y); o.z=f2b(v.z); o.w=f2b(v.w);
  } else {
    float vs[4];
    #pragma unroll
    for (int j=0;j<4;j++) vs[j] = (c+j<Cin)? in[(size_t)r*Cin+c+j] : 0.f;
    o.x=f2b(vs[0]); o.y=f2b(vs[1]); o.z=f2b(vs[2]); o.w=f2b(vs[3]);
  }
  *(ushort4*)(out+i) = o;
}

// out[c][r] = in[r][c] * (scale?scale[r]:1), bf16, zero-pad outside [R][C].
__global__ void k_trcvt(const float* __restrict__ in, u16* __restrict__ out,
                        int R, int C, int OCols, const float* __restrict__ scale){
  __shared__ float t[32][33];
  int c0 = blockIdx.x*32, r0 = blockIdx.y*32;
  int tx = threadIdx.x & 31, ty = threadIdx.x >> 5;
  #pragma unroll
  for (int i=0;i<4;i++){
    int r = r0 + ty + i*8, c = c0 + tx;
    float v = (r<R && c<C) ? in[(size_t)r*C + c] : 0.f;
    if (scale && r<R) v *= scale[r];
    t[ty+i*8][tx] = v;
  }
  __syncthreads();
  #pragma unroll
  for (int i=0;i<4;i++){
    int c = c0 + ty + i*8, r = r0 + tx;
    out[(size_t)c*OCols + r] = f2b(t[tx][ty+i*8]);
  }
}

// p rows appended to qT (cols 512/513 of G = denominators)
__global__ void k_prow(const float* __restrict__ pA, const float* __restrict__ pB,
                       u16* __restrict__ qT){
  int i = blockIdx.x*256 + threadIdx.x;
  qT[(size_t)512*N_NODES + i] = f2b(pA[i]);
  qT[(size_t)513*N_NODES + i] = f2b(pB[i]);
}

// ------- MFMA GEMM, reg-staged A with conversion, swizzled LDS -------
// C[M,N] = A[M,K] @ B^T, B [N][ldb] bf16 zero-padded. M-fastest grid:
// grid (M/BM, N/BN, SPLITK). ATYPE 0 = f32 (stacked pair, split srow),
// 1 = int32 mask -> 0/1. Slab z covers K rows [z*kcount, ...).
template<int BM, int BN, int ATYPE, int CTYPE>
__global__ __launch_bounds__(256) void k_mg(
    const void* __restrict__ A0v, const void* __restrict__ A1v, int srow,
    const u16* __restrict__ B, void* __restrict__ Cv,
    int M, int Nn, int K, int lda, int ldb, int ldc, int kcount){
  constexpr int WM = BM/2, WN = BN/2, MR = WM/16, NR = WN/16;
  __shared__ __align__(16) u16 sA[BM*64];
  __shared__ __align__(16) u16 sB[BN*64];
  const int tid = threadIdx.x;
  const int bm = blockIdx.x*BM, bn = blockIdx.y*BN;
  const int lane = tid & 63, w = tid >> 6;
  const int wr = w >> 1, wc = w & 1;
  f32x4 acc[MR][NR] = {};

  const int kbeg = blockIdx.z * kcount;
  const int kend = min(K, kbeg + kcount);

  for (int kk = kbeg; kk < kend; kk += 64){
    const int rem = kend - kk;
    #pragma unroll
    for (int p = 0; p < BM/32; p++){
      int idx = (p*256 + tid)*8;
      int row = idx >> 6, col = idx & 63;
      int grow = bm + row;
      us8 o;
      if (ATYPE == 0){
        const float* Ar = (grow < srow) ? ((const float*)A0v + (size_t)grow*lda + kk)
                                        : ((const float*)A1v + (size_t)(grow-srow)*lda + kk);
        if (col + 8 <= rem){
          float4 v0 = *(const float4*)(Ar + col);
          float4 v1 = *(const float4*)(Ar + col + 4);
          o[0]=f2b(v0.x); o[1]=f2b(v0.y); o[2]=f2b(v0.z); o[3]=f2b(v0.w);
          o[4]=f2b(v1.x); o[5]=f2b(v1.y); o[6]=f2b(v1.z); o[7]=f2b(v1.w);
        } else {
          #pragma unroll
          for (int j=0;j<8;j++) o[j] = (col+j < rem) ? f2b(Ar[col+j]) : (u16)0;
        }
      } else {
        const int* Ar = (const int*)A0v + (size_t)grow*lda + kk;
        if (col + 8 <= rem){
          int4 v0 = *(const int4*)(Ar + col);
          int4 v1 = *(const int4*)(Ar + col + 4);
          o[0]=v0.x?0x3f80:0; o[1]=v0.y?0x3f80:0; o[2]=v0.z?0x3f80:0; o[3]=v0.w?0x3f80:0;
          o[4]=v1.x?0x3f80:0; o[5]=v1.y?0x3f80:0; o[6]=v1.z?0x3f80:0; o[7]=v1.w?0x3f80:0;
        } else {
          #pragma unroll
          for (int j=0;j<8;j++) o[j] = (col+j < rem && Ar[col+j]) ? (u16)0x3f80 : (u16)0;
        }
      }
      *(us8*)((char*)sA + swz(row, col*2)) = o;
    }
    #pragma unroll
    for (int p = 0; p < BN/32; p++){
      int idx = (p*256 + tid)*8;
      int row = idx >> 6, col = idx & 63;
      us8 o = *(const us8*)(B + (size_t)(bn+row)*ldb + kk + col);
      *(us8*)((char*)sB + swz(row, col*2)) = o;
    }
    __syncthreads();
    #pragma unroll
    for (int ks = 0; ks < 2; ks++){
      bf16x8 af[MR], bfr[NR];
      #pragma unroll
      for (int m=0;m<MR;m++)
        af[m] = *(const bf16x8*)((char*)sA + swz(wr*WM + m*16 + (lane&15), ks*64 + (lane>>4)*16));
      #pragma unroll
      for (int n=0;n<NR;n++)
        bfr[n] = *(const bf16x8*)((char*)sB + swz(wc*WN + n*16 + (lane&15), ks*64 + (lane>>4)*16));
      #pragma unroll
      for (int m=0;m<MR;m++)
        #pragma unroll
        for (int n=0;n<NR;n++)
          acc[m][n] = __builtin_amdgcn_mfma_f32_16x16x32_bf16(af[m], bfr[n], acc[m][n], 0,0,0);
    }
    __syncthreads();
  }

  const size_t slab = (size_t)blockIdx.z * (size_t)M * ldc;
  const int rbase = bm + wr*WM + ((lane>>4)<<2);
  const int cbase = bn + wc*WN + (lane&15);
  if (CTYPE == 1){
    u16* C = (u16*)Cv + slab;
    #pragma unroll
    for (int m=0;m<MR;m++)
      #pragma unroll
      for (int n=0;n<NR;n++)
        #pragma unroll
        for (int j=0;j<4;j++)
          C[(size_t)(rbase + m*16 + j)*ldc + cbase + n*16] = f2b(acc[m][n][j]);
  } else {
    float* C = (float*)Cv + slab;
    #pragma unroll
    for (int m=0;m<MR;m++)
      #pragma unroll
      for (int n=0;n<NR;n++)
        #pragma unroll
        for (int j=0;j<4;j++)
          C[(size_t)(rbase + m*16 + j)*ldc + cbase + n*16] = acc[m][n][j];
  }
}

// ---------------- proj slab-reduce fused with GAT1 scores ----------------
__global__ void k_hred(const float* __restrict__ S, float* __restrict__ h,
                       const float* __restrict__ a_src, const float* __restrict__ a_dst,
                       float* __restrict__ ss, float* __restrict__ sd){
  const size_t SLP = (size_t)2*N_NODES*HIDC;
  int n = blockIdx.x, c = threadIdx.x;
  size_t i = (size_t)n*HIDC + c;
  float v = S[i] + S[i+SLP] + S[i+2*SLP] + S[i+3*SLP];
  h[i] = v;
  float vs = v*a_src[c], vd = v*a_dst[c];
  #pragma unroll
  for (int o=32;o>0;o>>=1){ vs += __shfl_down(vs,o); vd += __shfl_down(vd,o); }
  if ((c&63)==0){ int hh=c>>6; ss[n*4+hh]=vs; sd[n*4+hh]=vd; }
}

// ---------------- GAT layer 1 (4 heads x 64 ch) ----------------
__global__ void k_gat1(const float* __restrict__ h1, const float* __restrict__ s_src,
                       const float* __restrict__ s_dst, const int* __restrict__ off,
                       const int* __restrict__ csr_src, const float* __restrict__ csr_w,
                       const float* __restrict__ b1, float* __restrict__ z){
  int n = blockIdx.x, c = threadIdx.x, h = c>>6;
  int o0 = off[n], o1 = off[n+1];
  float sd = s_dst[n*4+h];
  float m = -1e30f;
  for (int t=o0;t<o1;t++){
    int s = csr_src[t];
    m = fmaxf(m, lrelu(s_src[s*4+h]+sd));
  }
  float denom=0.f, acc=0.f;
  for (int t=o0;t<o1;t++){
    int s = csr_src[t];
    float wv = expf(lrelu(s_src[s*4+h]+sd)-m)*csr_w[t];
    denom += wv;
    acc += wv * h1[(size_t)s*HIDC + c];
  }
  float res = acc/(denom+1e-16f) + b1[c];
  z[(size_t)n*HIDC+c] = fmaxf(res, 0.f);
}

// ---------------- GAT layer 2 (1 head x 3000 ch, h2 bf16 ld=NPAD) ----------------
__global__ void k_scores2(const u16* __restrict__ h2, const float* __restrict__ a_src,
                          const float* __restrict__ a_dst, float* __restrict__ s_src,
                          float* __restrict__ s_dst){
  __shared__ float sm[8];
  int n = blockIdx.x, tid = threadIdx.x;
  const u16* row = h2 + (size_t)n*NPAD;
  float vs=0.f, vd=0.f;
  for (int c = tid*8; c < F_INF; c += 2048){
    ushort4 u0 = *(const ushort4*)(row + c);
    ushort4 u1 = *(const ushort4*)(row + c + 4);
    float f0=b2f(u0.x), f1=b2f(u0.y), f2=b2f(u0.z), f3=b2f(u0.w);
    float f4=b2f(u1.x), f5=b2f(u1.y), f6=b2f(u1.z), f7=b2f(u1.w);
    vs += f0*a_src[c]+f1*a_src[c+1]+f2*a_src[c+2]+f3*a_src[c+3]
        + f4*a_src[c+4]+f5*a_src[c+5]+f6*a_src[c+6]+f7*a_src[c+7];
    vd += f0*a_dst[c]+f1*a_dst[c+1]+f2*a_dst[c+2]+f3*a_dst[c+3]
        + f4*a_dst[c+4]+f5*a_dst[c+5]+f6*a_dst[c+6]+f7*a_dst[c+7];
  }
  #pragma unroll
  for (int o=32;o>0;o>>=1){ vs+=__shfl_down(vs,o); vd+=__shfl_down(vd,o); }
  int lane=tid&63, w=tid>>6;
  if (lane==0){ sm[w]=vs; sm[4+w]=vd; }
  __syncthreads();
  if (tid==0) s_src[n]=sm[0]+sm[1]+sm[2]+sm[3];
  if (tid==1) s_dst[n]=sm[4]+sm[5]+sm[6]+sm[7];
}

__global__ void k_gat2(const u16* __restrict__ h2, const float* __restrict__ s_src,
                       const float* __restrict__ s_dst, const int* __restrict__ off,
                       const int* __restrict__ csr_src, const float* __restrict__ csr_w,
                       const float* __restrict__ b2, float* __restrict__ hout){
  int n = blockIdx.x, tid = threadIdx.x;
  int o0=off[n], o1=off[n+1];
  float sd = s_dst[n];
  float m=-1e30f;
  for (int t=o0;t<o1;t++) m = fmaxf(m, lrelu(s_src[csr_src[t]]+sd));
  float denom=0.f;
  float acc[12];
  #pragma unroll
  for (int k=0;k<12;k++) acc[k]=0.f;
  int c0 = tid*12;
  bool act = c0 < F_INF;
  for (int t=o0;t<o1;t++){
    int s=csr_src[t];
    float wv = expf(lrelu(s_src[s]+sd)-m)*csr_w[t];
    denom += wv;
    if (act){
      const ushort4* r4 = (const ushort4*)(h2 + (size_t)s*NPAD + c0);
      #pragma unroll
      for (int v=0;v<3;v++){
        ushort4 u = r4[v];
        acc[v*4+0] += wv*b2f(u.x);
        acc[v*4+1] += wv*b2f(u.y);
        acc[v*4+2] += wv*b2f(u.z);
        acc[v*4+3] += wv*b2f(u.w);
      }
    }
  }
  float inv = 1.f/(denom+1e-16f);
  if (act){
    #pragma unroll
    for (int k=0;k<12;k++)
      hout[(size_t)n*F_INF + c0 + k] = acc[k]*inv + b2[c0+k];
  }
}

// ---------------- attention pooling ----------------
__global__ void k_pool(const float* __restrict__ emb, const float* __restrict__ w1,
                       const float* __restrict__ b1, const float* __restrict__ w2,
                       const float* __restrict__ b2, float* __restrict__ scores){
  __shared__ float ze[HIDC];
  __shared__ float red[POOLH];
  int n = blockIdx.x, t = threadIdx.x;
  ze[t]     = emb[(size_t)n*HIDC + t];
  ze[t+128] = emb[(size_t)n*HIDC + t + 128];
  __syncthreads();
  float acc = b1[t];
  for (int d=0; d<HIDC; d++) acc += ze[d]*w1[d*POOLH + t];
  float hidden = fmaxf(acc, 0.f);
  red[t] = hidden * w2[t];
  __syncthreads();
  for (int s=64; s>0; s>>=1){
    if (t < s) red[t] += red[t+s];
    __syncthreads();
  }
  if (t==0) scores[n] = red[0] + b2[0];
}

__global__ void k_maxred(const float* __restrict__ s, float* __restrict__ M){
  __shared__ float sm[16];
  int tid=threadIdx.x;
  float m=-1e30f;
  for (int i=tid;i<N_NODES;i+=1024) m=fmaxf(m,s[i]);
  #pragma unroll
  for (int o=32;o>0;o>>=1) m=fmaxf(m,__shfl_down(m,o));
  if ((tid&63)==0) sm[tid>>6]=m;
  __syncthreads();
  if (tid==0){
    float mm=sm[0];
    for (int i=1;i<16;i++) mm=fmaxf(mm,sm[i]);
    M[0]=mm;
  }
}

__global__ void k_p(const float* __restrict__ s, const float* __restrict__ M,
                    float* __restrict__ p){
  int i=blockIdx.x*256+threadIdx.x;
  if (i<N_NODES) p[i]=expf(s[i]-M[0]);
}

// sums 4 split-K slabs of G [4096][576]; dn from cols 512/513; norm + sigmoid
__global__ void k_gfin(const float* __restrict__ G, float* __restrict__ g,
                       int co, int dcol){
  __shared__ float sm[4];
  __shared__ float tot;
  const size_t SL = (size_t)N_NODES*GCOLS;
  int n=blockIdx.x, c=threadIdx.x;
  size_t base = (size_t)n*GCOLS;
  float gp=0.f, dn=0.f;
  #pragma unroll
  for (int s=0;s<4;s++){ gp += G[base+co+c+s*SL]; dn += G[base+dcol+s*SL]; }
  gp /= (dn + 1e-16f);
  float v = gp*gp;
  #pragma unroll
  for (int o=32;o>0;o>>=1) v+=__shfl_down(v,o);
  if ((c&63)==0) sm[c>>6]=v;
  __syncthreads();
  if (c==0) tot = sm[0]+sm[1]+sm[2]+sm[3];
  __syncthreads();
  float nrm = sqrtf(tot);
  float x = gp/fmaxf(nrm,1e-12f);
  g[(size_t)n*HIDC+c]=1.f/(1.f+expf(-x));
}

// ---------------- discriminator ----------------
__global__ void k_disc(const float* __restrict__ z, const float* __restrict__ za,
                       const float* __restrict__ V, const float* __restrict__ Va,
                       const float* __restrict__ bbp, const float* __restrict__ biasp,
                       float* __restrict__ ret, float* __restrict__ ret_a){
  __shared__ float sm[16];
  int n=blockIdx.x, c=threadIdx.x;
  float ez = z[(size_t)n*HIDC+c], ea = za[(size_t)n*HIDC+c];
  float v  = V[(size_t)n*HIDC+c], va = Va[(size_t)n*HIDC+c];
  float p1=ez*v, p2=ea*v, p3=ea*va, p4=ez*va;
  #pragma unroll
  for (int o=32;o>0;o>>=1){
    p1+=__shfl_down(p1,o); p2+=__shfl_down(p2,o);
    p3+=__shfl_down(p3,o); p4+=__shfl_down(p4,o);
  }
  int lane=c&63, w=c>>6;
  if (lane==0){ sm[w]=p1; sm[4+w]=p2; sm[8+w]=p3; sm[12+w]=p4; }
  __syncthreads();
  if (c==0){
    float add = bbp[0]+biasp[0];
    ret[n*2+0]   = sm[0]+sm[1]+sm[2]+sm[3]   + add;
    ret[n*2+1]   = sm[4]+sm[5]+sm[6]+sm[7]   + add;
    ret_a[n*2+0] = sm[8]+sm[9]+sm[10]+sm[11] + add;
    ret_a[n*2+1] = sm[12]+sm[13]+sm[14]+sm[15] + add;
  }
}

extern "C" void kernel_launch(void* const* d_in, const int* in_sizes, int n_in,
                              void* d_out, int out_size, void* d_ws, size_t ws_size,
                              hipStream_t stream){
  (void)in_sizes; (void)n_in; (void)out_size; (void)ws_size;
  const float* feat   = (const float*)d_in[0];
  const float* feat_a = (const float*)d_in[1];
  const int*   ei     = (const int*)d_in[2];
  const float* ew     = (const float*)d_in[3];
  const int*   mask   = (const int*)d_in[4];
  const float* W1     = (const float*)d_in[5];
  const float* a_src1 = (const float*)d_in[6];
  const float* a_dst1 = (const float*)d_in[7];
  const float* b1     = (const float*)d_in[8];
  const float* W2     = (const float*)d_in[9];
  const float* a_src2 = (const float*)d_in[10];
  const float* a_dst2 = (const float*)d_in[11];
  const float* b2     = (const float*)d_in[12];
  const float* pw1    = (const float*)d_in[13];
  const float* pb1    = (const float*)d_in[14];
  const float* pw2    = (const float*)d_in[15];
  const float* pb2    = (const float*)d_in[16];
  const float* dw     = (const float*)d_in[17];
  const float* dbb    = (const float*)d_in[18];
  const float* dbias  = (const float*)d_in[19];

  float* out  = (float*)d_out;
  float* z    = out;
  float* hout = out + (size_t)N_NODES*HIDC;
  float* ret  = hout + (size_t)N_NODES*F_INF;
  float* ret_a= ret + (size_t)N_NODES*2;

  char* cur = (char*)d_ws;
  auto alloc = [&](size_t bytes)->void*{
    void* p = cur; cur += (bytes + 255) & ~(size_t)255; return p;
  };
  // SLB: time-shared region — proj slabs (f32, 32MB) -> h2b (bf16, 24MB)
  //      -> mask slabs (f32, 37.7MB). Strictly sequential uses.
  void* SLB = alloc((size_t)4*N_NODES*GCOLS*4);
  u16* W1T  = (u16*)alloc((size_t)HIDC*FPAD*2);
  u16* W2T  = (u16*)alloc((size_t)NPAD*HIDC*2);
  u16* qT   = (u16*)alloc((size_t)GCOLS*N_NODES*2);
  u16* dwb  = (u16*)alloc((size_t)HIDC*HIDC*2);
  float* h1st = (float*)alloc((size_t)2*N_NODES*HIDC*4);
  float* za   = (float*)alloc((size_t)N_NODES*HIDC*4);
  float* Vst  = (float*)alloc((size_t)2*N_NODES*HIDC*4);
  float* gv   = (float*)alloc((size_t)N_NODES*HIDC*4);
  float* gva  = (float*)alloc((size_t)N_NODES*HIDC*4);
  float* ss1 = (float*)alloc((size_t)2*N_NODES*4*4);
  float* sd1 = (float*)alloc((size_t)2*N_NODES*4*4);
  float* ss2 = (float*)alloc(N_NODES*4);
  float* sd2 = (float*)alloc(N_NODES*4);
  float* scA = (float*)alloc(N_NODES*4);
  float* scB = (float*)alloc(N_NODES*4);
  float* pvA = (float*)alloc(N_NODES*4);
  float* pvB = (float*)alloc(N_NODES*4);
  float* MbA = (float*)alloc(256);
  float* MbB = (float*)alloc(256);
  int* deg    = (int*)alloc(N_NODES*4);
  int* off    = (int*)alloc((N_NODES+64)*4);
  int* cursor = (int*)alloc(N_NODES*4);
  int* csrc   = (int*)alloc(NEDGE*4);
  float* csw  = (float*)alloc(NEDGE*4);

  float* h1  = h1st;
  float* h1a = h1st + (size_t)N_NODES*HIDC;
  float* V   = Vst;
  float* Va  = Vst + (size_t)N_NODES*HIDC;

  // ---- CSR build ----
  hipMemsetAsync(deg, 0, N_NODES*sizeof(int), stream);
  hipMemsetAsync(cursor, 0, N_NODES*sizeof(int), stream);
  hipMemsetAsync(qT + (size_t)514*N_NODES, 0, (size_t)(GCOLS-514)*N_NODES*2, stream);
  k_deg<<<NEDGE/256,256,0,stream>>>(ei+NEDGE, deg);
  k_scan<<<1,1024,0,stream>>>(deg, off);
  k_fill<<<NEDGE/256,256,0,stream>>>(ei, ew, off, cursor, csrc, csw);

  // ---- weight conversions ----
  k_trcvt<<<dim3(HIDC/32, FPAD/32),256,0,stream>>>(W1, W1T, F_INF, HIDC, FPAD, nullptr);
  k_trcvt<<<dim3(NPAD/32, HIDC/32),256,0,stream>>>(W2, W2T, HIDC, F_INF, HIDC, nullptr);
  k_cvt<<<HIDC*HIDC/4/256,256,0,stream>>>(dw, dwb, HIDC, HIDC, HIDC);

  // ---- stacked projection, split-K=4: slabs = [feat;feat_a] @ W1 ----
  k_mg<128,64,0,0><<<dim3(2*N_NODES/128, HIDC/64, 4),256,0,stream>>>(
      feat, feat_a, N_NODES, W1T, SLB, 2*N_NODES, HIDC, F_INF, F_INF, FPAD, HIDC, 768);
  k_hred<<<2*N_NODES,256,0,stream>>>((const float*)SLB, h1st, a_src1, a_dst1, ss1, sd1);

  // ---- GAT1 both branches ----
  k_gat1<<<N_NODES,256,0,stream>>>(h1, ss1, sd1, off, csrc, csw, b1, z);
  k_gat1<<<N_NODES,256,0,stream>>>(h1a, ss1 + (size_t)N_NODES*4, sd1 + (size_t)N_NODES*4,
                                   off, csrc, csw, b1, za);

  // ---- GAT2: h2 = z @ W2 (bf16 into SLB), then aggregate ----
  u16* h2b = (u16*)SLB;
  k_mg<128,128,0,1><<<dim3(N_NODES/128, NPAD/128, 1),256,0,stream>>>(
      z, z, N_NODES, W2T, h2b, N_NODES, NPAD, HIDC, HIDC, HIDC, NPAD, HIDC);
  k_scores2<<<N_NODES,256,0,stream>>>(h2b, a_src2, a_dst2, ss2, sd2);
  k_gat2<<<N_NODES,256,0,stream>>>(h2b, ss2, sd2, off, csrc, csw, b2, hout);

  // ---- pooling scores + softmax numerators ----
  k_pool<<<N_NODES,128,0,stream>>>(z,  pw1, pb1, pw2, pb2, scA);
  k_pool<<<N_NODES,128,0,stream>>>(za, pw1, pb1, pw2, pb2, scB);
  k_maxred<<<1,1024,0,stream>>>(scA, MbA);
  k_maxred<<<1,1024,0,stream>>>(scB, MbB);
  k_p<<<N_NODES/256,256,0,stream>>>(scA, MbA, pvA);
  k_p<<<N_NODES/256,256,0,stream>>>(scB, MbB, pvB);
  k_trcvt<<<dim3(HIDC/32, N_NODES/32),256,0,stream>>>(z,  qT, N_NODES, HIDC, N_NODES, pvA);
  k_trcvt<<<dim3(HIDC/32, N_NODES/32),256,0,stream>>>(za, qT + (size_t)HIDC*N_NODES, N_NODES, HIDC, N_NODES, pvB);
  k_prow<<<N_NODES/256,256,0,stream>>>(pvA, pvB, qT);

  // ---- masked-softmax GEMM: G = Mask @ [q | qa | pA | pB], split-K=4 ----
  k_mg<128,64,1,0><<<dim3(N_NODES/128, GCOLS/64, 4),256,0,stream>>>(
      mask, mask, 2*N_NODES, qT, SLB, N_NODES, GCOLS, N_NODES, N_NODES, N_NODES, GCOLS, 1024);
  k_gfin<<<N_NODES,256,0,stream>>>((const float*)SLB, gv, 0, 512);
  k_gfin<<<N_NODES,256,0,stream>>>((const float*)SLB, gva, HIDC, 513);

  // ---- discriminator: [V;Va] = [gv;gva] @ dw^T ----
  k_mg<128,64,0,0><<<dim3(2*N_NODES/128, HIDC/64, 1),256,0,stream>>>(
      gv, gva, N_NODES, dwb, Vst, 2*N_NODES, HIDC, HIDC, HIDC, HIDC, HIDC, HIDC);
  k_disc<<<N_NODES,256,0,stream>>>(z, za, V, Va, dbb, dbias, ret, ret_a);
}

// Round 5
// 336.292 us; speedup vs baseline: 7.1980x; 1.1691x over previous
//
#include <hip/hip_runtime.h>
#include <cstdint>
#include <cstddef>

#define N_NODES 4096
#define F_INF   3000
#define FPAD    3008
#define NPAD    3072
#define HIDC    256
#define NEDGE   65536
#define POOLH   128
#define GCOLS   576   // 256 (branch1) + 256 (branchA) + dnA + dnB + pad

typedef unsigned short u16;
typedef __attribute__((ext_vector_type(8))) short bf16x8;
typedef __attribute__((ext_vector_type(8))) unsigned short us8;
typedef __attribute__((ext_vector_type(4))) float f32x4;

__device__ inline float lrelu(float x){ return x > 0.f ? x : 0.2f*x; }
__device__ inline u16 f2b(float f){
  uint32_t x = __builtin_bit_cast(uint32_t, f);
  uint32_t r = (x + 0x7fffu + ((x >> 16) & 1u)) >> 16;
  return (u16)r;
}
__device__ inline float b2f(u16 u){
  uint32_t x = ((uint32_t)u) << 16;
  return __builtin_bit_cast(float, x);
}
// XOR swizzle for [row][64 bf16] tiles (128B rows): conflict-free b128 r/w.
__device__ __forceinline__ int swz(int row, int cb){
  return row*128 + (cb ^ ((row & 7) << 4));
}

// ---------------- CSR build ----------------
__global__ void k_deg(const int* __restrict__ dst, int* __restrict__ deg){
  int e = blockIdx.x*256 + threadIdx.x;
  if (e < NEDGE) atomicAdd(&deg[dst[e]], 1);
}

__global__ void k_scan(const int* __restrict__ deg, int* __restrict__ off){
  __shared__ int sm[1024];
  int tid = threadIdx.x;
  int v0=deg[tid*4], v1=deg[tid*4+1], v2=deg[tid*4+2], v3=deg[tid*4+3];
  int s = v0+v1+v2+v3;
  sm[tid]=s; __syncthreads();
  for (int d=1; d<1024; d<<=1){
    int t = (tid>=d)? sm[tid-d] : 0;
    __syncthreads();
    sm[tid] += t;
    __syncthreads();
  }
  int run = sm[tid]-s;
  off[tid*4+0]=run; run+=v0;
  off[tid*4+1]=run; run+=v1;
  off[tid*4+2]=run; run+=v2;
  off[tid*4+3]=run; run+=v3;
  if (tid==1023) off[N_NODES]=run;
}

__global__ void k_fill(const int* __restrict__ ei, const float* __restrict__ ew,
                       const int* __restrict__ off, int* __restrict__ cursor,
                       int* __restrict__ csr_src, float* __restrict__ csr_w){
  int e = blockIdx.x*256+threadIdx.x;
  if (e >= NEDGE) return;
  int d = ei[NEDGE + e];
  int slot = off[d] + atomicAdd(&cursor[d],1);
  csr_src[slot] = ei[e];
  csr_w[slot] = ew[e];
}

// ---------------- conversions ----------------
__global__ void k_cvt(const float* __restrict__ in, u16* __restrict__ out,
                      int R, int Cin, int Cout){
  size_t i = ((size_t)blockIdx.x*256 + threadIdx.x)*4;
  if (i >= (size_t)R*Cout) return;
  int r = (int)(i / Cout), c = (int)(i % Cout);
  ushort4 o;
  if (c + 3 < Cin){
    float4 v = *(const float4*)(in + (size_t)r*Cin + c);
    o.x=f2b(v.x); o.y=f2b(v.y); o.z=f2b(v.z); o.w=f2b(v.w);
  } else {
    float vs[4];
    #pragma unroll
    for (int j=0;j<4;j++) vs[j] = (c+j<Cin)? in[(size_t)r*Cin+c+j] : 0.f;
    o.x=f2b(vs[0]); o.y=f2b(vs[1]); o.z=f2b(vs[2]); o.w=f2b(vs[3]);
  }
  *(ushort4*)(out+i) = o;
}

// out[c][r] = in[r][c] * (scale?scale[r]:1), bf16, zero-pad outside [R][C].
__global__ void k_trcvt(const float* __restrict__ in, u16* __restrict__ out,
                        int R, int C, int OCols, const float* __restrict__ scale){
  __shared__ float t[32][33];
  int c0 = blockIdx.x*32, r0 = blockIdx.y*32;
  int tx = threadIdx.x & 31, ty = threadIdx.x >> 5;
  #pragma unroll
  for (int i=0;i<4;i++){
    int r = r0 + ty + i*8, c = c0 + tx;
    float v = (r<R && c<C) ? in[(size_t)r*C + c] : 0.f;
    if (scale && r<R) v *= scale[r];
    t[ty+i*8][tx] = v;
  }
  __syncthreads();
  #pragma unroll
  for (int i=0;i<4;i++){
    int c = c0 + ty + i*8, r = r0 + tx;
    out[(size_t)c*OCols + r] = f2b(t[tx][ty+i*8]);
  }
}

// ------- MFMA GEMM, T14 prefetch: reg-stage(+cvt) -> swizzled LDS -------
// C[M,N] = A[M,K] @ B^T, B [N][ldb] bf16 zero-padded. grid (M/BM, N/BN, SPLITK).
// ATYPE 0 = f32 (stacked pair split at srow), 1 = int32 mask -> 0/1 bf16.
template<int BM, int BN, int ATYPE, int CTYPE>
__global__ __launch_bounds__(256) void k_mg(
    const void* __restrict__ A0v, const void* __restrict__ A1v, int srow,
    const u16* __restrict__ B, void* __restrict__ Cv,
    int M, int Nn, int K, int lda, int ldb, int ldc, int kcount){
  constexpr int WM = BM/2, WN = BN/2, MR = WM/16, NR = WN/16;
  constexpr int AP = BM/32, BP = BN/32;
  __shared__ __align__(16) u16 sA[BM*64];
  __shared__ __align__(16) u16 sB[BN*64];
  const int tid = threadIdx.x;
  const int bm = blockIdx.x*BM, bn = blockIdx.y*BN;
  const int lane = tid & 63, w = tid >> 6;
  const int wr = w >> 1, wc = w & 1;
  f32x4 acc[MR][NR] = {};

  const int kbeg = blockIdx.z * kcount;
  const int kend = min(K, kbeg + kcount);

  float afr[AP][8];   // ATYPE 0 staging regs
  int   air[AP][8];   // ATYPE 1 staging regs
  us8   brr[BP];      // B staging regs

  auto loadA = [&](int kk2, int rem2){
    #pragma unroll
    for (int p=0;p<AP;p++){
      int idx=(p*256+tid)*8, row=idx>>6, col=idx&63, grow=bm+row;
      if (ATYPE==0){
        const float* Ar = (grow<srow)? ((const float*)A0v+(size_t)grow*lda+kk2)
                                     : ((const float*)A1v+(size_t)(grow-srow)*lda+kk2);
        if (col+8<=rem2){
          float4 v0=*(const float4*)(Ar+col), v1=*(const float4*)(Ar+col+4);
          afr[p][0]=v0.x; afr[p][1]=v0.y; afr[p][2]=v0.z; afr[p][3]=v0.w;
          afr[p][4]=v1.x; afr[p][5]=v1.y; afr[p][6]=v1.z; afr[p][7]=v1.w;
        } else {
          #pragma unroll
          for (int j=0;j<8;j++) afr[p][j] = (col+j<rem2)? Ar[col+j] : 0.f;
        }
      } else {
        const int* Ar=(const int*)A0v+(size_t)grow*lda+kk2;
        if (col+8<=rem2){
          int4 v0=*(const int4*)(Ar+col), v1=*(const int4*)(Ar+col+4);
          air[p][0]=v0.x; air[p][1]=v0.y; air[p][2]=v0.z; air[p][3]=v0.w;
          air[p][4]=v1.x; air[p][5]=v1.y; air[p][6]=v1.z; air[p][7]=v1.w;
        } else {
          #pragma unroll
          for (int j=0;j<8;j++) air[p][j] = (col+j<rem2)? Ar[col+j] : 0;
        }
      }
    }
  };
  auto loadB = [&](int kk2){
    #pragma unroll
    for (int p=0;p<BP;p++){
      int idx=(p*256+tid)*8, row=idx>>6, col=idx&63;
      brr[p] = *(const us8*)(B+(size_t)(bn+row)*ldb+kk2+col);
    }
  };
  auto store = [&](){
    #pragma unroll
    for (int p=0;p<AP;p++){
      int idx=(p*256+tid)*8, row=idx>>6, col=idx&63;
      us8 o;
      #pragma unroll
      for (int j=0;j<8;j++)
        o[j] = (ATYPE==0)? f2b(afr[p][j]) : (air[p][j] ? (u16)0x3f80 : (u16)0);
      *(us8*)((char*)sA + swz(row, col*2)) = o;
    }
    #pragma unroll
    for (int p=0;p<BP;p++){
      int idx=(p*256+tid)*8, row=idx>>6, col=idx&63;
      *(us8*)((char*)sB + swz(row, col*2)) = brr[p];
    }
  };

  loadA(kbeg, kend-kbeg); loadB(kbeg);
  for (int kk=kbeg; kk<kend; kk+=64){
    store();
    __syncthreads();
    int kn = kk+64;
    if (kn < kend){ loadA(kn, kend-kn); loadB(kn); }  // prefetch: overlaps MFMA
    #pragma unroll
    for (int ks=0;ks<2;ks++){
      bf16x8 af[MR], bfr[NR];
      #pragma unroll
      for (int m=0;m<MR;m++)
        af[m] = *(const bf16x8*)((char*)sA + swz(wr*WM + m*16 + (lane&15), ks*64 + (lane>>4)*16));
      #pragma unroll
      for (int n=0;n<NR;n++)
        bfr[n] = *(const bf16x8*)((char*)sB + swz(wc*WN + n*16 + (lane&15), ks*64 + (lane>>4)*16));
      #pragma unroll
      for (int m=0;m<MR;m++)
        #pragma unroll
        for (int n=0;n<NR;n++)
          acc[m][n] = __builtin_amdgcn_mfma_f32_16x16x32_bf16(af[m], bfr[n], acc[m][n], 0,0,0);
    }
    __syncthreads();
  }

  const size_t slab = (size_t)blockIdx.z * (size_t)M * ldc;
  const int rbase = bm + wr*WM + ((lane>>4)<<2);
  const int cbase = bn + wc*WN + (lane&15);
  if (CTYPE == 1){
    u16* C = (u16*)Cv + slab;
    #pragma unroll
    for (int m=0;m<MR;m++)
      #pragma unroll
      for (int n=0;n<NR;n++)
        #pragma unroll
        for (int j=0;j<4;j++)
          C[(size_t)(rbase + m*16 + j)*ldc + cbase + n*16] = f2b(acc[m][n][j]);
  } else {
    float* C = (float*)Cv + slab;
    #pragma unroll
    for (int m=0;m<MR;m++)
      #pragma unroll
      for (int n=0;n<NR;n++)
        #pragma unroll
        for (int j=0;j<4;j++)
          C[(size_t)(rbase + m*16 + j)*ldc + cbase + n*16] = acc[m][n][j];
  }
}

// ---------------- proj slab-reduce fused with GAT1 scores ----------------
__global__ void k_hred(const float* __restrict__ S, float* __restrict__ h,
                       const float* __restrict__ a_src, const float* __restrict__ a_dst,
                       float* __restrict__ ss, float* __restrict__ sd){
  const size_t SLP = (size_t)2*N_NODES*HIDC;
  int n = blockIdx.x, c = threadIdx.x;
  size_t i = (size_t)n*HIDC + c;
  float v = S[i] + S[i+SLP] + S[i+2*SLP] + S[i+3*SLP];
  h[i] = v;
  float vs = v*a_src[c], vd = v*a_dst[c];
  #pragma unroll
  for (int o=32;o>0;o>>=1){ vs += __shfl_down(vs,o); vd += __shfl_down(vd,o); }
  if ((c&63)==0){ int hh=c>>6; ss[n*4+hh]=vs; sd[n*4+hh]=vd; }
}

// ---------------- GAT layer 1 (both branches, grid 2N) ----------------
__global__ void k_gat1(const float* __restrict__ h1st, const float* __restrict__ s_src,
                       const float* __restrict__ s_dst, const int* __restrict__ off,
                       const int* __restrict__ csr_src, const float* __restrict__ csr_w,
                       const float* __restrict__ b1, float* __restrict__ z,
                       float* __restrict__ za){
  int nb = blockIdx.x, c = threadIdx.x, h = c>>6;
  int n = nb & (N_NODES-1), br = nb >> 12;
  const float* hm = h1st + (size_t)br*N_NODES*HIDC;
  const float* ssp = s_src + (size_t)br*N_NODES*4;
  const float* sdp = s_dst + (size_t)br*N_NODES*4;
  float* zp = br ? za : z;
  int o0 = off[n], o1 = off[n+1];
  float sd = sdp[n*4+h];
  float m = -1e30f;
  for (int t=o0;t<o1;t++){
    int s = csr_src[t];
    m = fmaxf(m, lrelu(ssp[s*4+h]+sd));
  }
  float denom=0.f, acc=0.f;
  for (int t=o0;t<o1;t++){
    int s = csr_src[t];
    float wv = expf(lrelu(ssp[s*4+h]+sd)-m)*csr_w[t];
    denom += wv;
    acc += wv * hm[(size_t)s*HIDC + c];
  }
  float res = acc/(denom+1e-16f) + b1[c];
  zp[(size_t)n*HIDC+c] = fmaxf(res, 0.f);
}

// ---------------- GAT layer 2 (h2 bf16 ld=NPAD) ----------------
__global__ void k_scores2(const u16* __restrict__ h2, const float* __restrict__ a_src,
                          const float* __restrict__ a_dst, float* __restrict__ s_src,
                          float* __restrict__ s_dst){
  __shared__ float sm[8];
  int n = blockIdx.x, tid = threadIdx.x;
  const u16* row = h2 + (size_t)n*NPAD;
  float vs=0.f, vd=0.f;
  for (int c = tid*8; c < F_INF; c += 2048){
    ushort4 u0 = *(const ushort4*)(row + c);
    ushort4 u1 = *(const ushort4*)(row + c + 4);
    float f0=b2f(u0.x), f1=b2f(u0.y), f2=b2f(u0.z), f3=b2f(u0.w);
    float f4=b2f(u1.x), f5=b2f(u1.y), f6=b2f(u1.z), f7=b2f(u1.w);
    vs += f0*a_src[c]+f1*a_src[c+1]+f2*a_src[c+2]+f3*a_src[c+3]
        + f4*a_src[c+4]+f5*a_src[c+5]+f6*a_src[c+6]+f7*a_src[c+7];
    vd += f0*a_dst[c]+f1*a_dst[c+1]+f2*a_dst[c+2]+f3*a_dst[c+3]
        + f4*a_dst[c+4]+f5*a_dst[c+5]+f6*a_dst[c+6]+f7*a_dst[c+7];
  }
  #pragma unroll
  for (int o=32;o>0;o>>=1){ vs+=__shfl_down(vs,o); vd+=__shfl_down(vd,o); }
  int lane=tid&63, w=tid>>6;
  if (lane==0){ sm[w]=vs; sm[4+w]=vd; }
  __syncthreads();
  if (tid==0) s_src[n]=sm[0]+sm[1]+sm[2]+sm[3];
  if (tid==1) s_dst[n]=sm[4]+sm[5]+sm[6]+sm[7];
}

__global__ void k_gat2(const u16* __restrict__ h2, const float* __restrict__ s_src,
                       const float* __restrict__ s_dst, const int* __restrict__ off,
                       const int* __restrict__ csr_src, const float* __restrict__ csr_w,
                       const float* __restrict__ b2, float* __restrict__ hout){
  int n = blockIdx.x, tid = threadIdx.x;   // 384 threads: 8 bf16 each = 3072
  int o0=off[n], o1=off[n+1];
  float sd = s_dst[n];
  float m=-1e30f;
  for (int t=o0;t<o1;t++) m = fmaxf(m, lrelu(s_src[csr_src[t]]+sd));
  float denom=0.f;
  float acc[8];
  #pragma unroll
  for (int j=0;j<8;j++) acc[j]=0.f;
  int c0 = tid*8;
  for (int t=o0;t<o1;t++){
    int s=csr_src[t];
    float wv = expf(lrelu(s_src[s]+sd)-m)*csr_w[t];
    denom += wv;
    us8 u = *(const us8*)(h2 + (size_t)s*NPAD + c0);
    #pragma unroll
    for (int j=0;j<8;j++) acc[j] += wv*b2f(u[j]);
  }
  float inv = 1.f/(denom+1e-16f);
  if (c0 < F_INF){
    #pragma unroll
    for (int j=0;j<8;j++)
      hout[(size_t)n*F_INF + c0 + j] = acc[j]*inv + b2[c0+j];
  }
}

// ---------------- pooling: scores from Hp slabs (wave per row) ----------------
__global__ void k_score(const float* __restrict__ Hp, const float* __restrict__ b1,
                        const float* __restrict__ w2, const float* __restrict__ b2,
                        float* __restrict__ sc){
  const size_t SLP = (size_t)2*N_NODES*POOLH;
  int row = blockIdx.x*4 + (threadIdx.x>>6);
  int lane = threadIdx.x & 63;
  size_t base = (size_t)row*POOLH;
  float h0 = fmaxf(Hp[base+lane]    + Hp[base+lane+SLP]    + b1[lane],    0.f);
  float h1 = fmaxf(Hp[base+lane+64] + Hp[base+lane+64+SLP] + b1[lane+64], 0.f);
  float v = h0*w2[lane] + h1*w2[lane+64];
  #pragma unroll
  for (int o=32;o>0;o>>=1) v += __shfl_down(v,o);
  if (lane==0) sc[row] = v + b2[0];
}

__global__ void k_maxred2(const float* __restrict__ s, float* __restrict__ M){
  __shared__ float sm[16];
  int tid=threadIdx.x;
  const float* sp = s + (size_t)blockIdx.x*N_NODES;
  float m=-1e30f;
  for (int i=tid;i<N_NODES;i+=1024) m=fmaxf(m,sp[i]);
  #pragma unroll
  for (int o=32;o>0;o>>=1) m=fmaxf(m,__shfl_down(m,o));
  if ((tid&63)==0) sm[tid>>6]=m;
  __syncthreads();
  if (tid==0){
    float mm=sm[0];
    for (int i=1;i<16;i++) mm=fmaxf(mm,sm[i]);
    M[blockIdx.x]=mm;
  }
}

__global__ void k_p2(const float* __restrict__ sc, const float* __restrict__ M,
                     float* __restrict__ pA, float* __restrict__ pB,
                     u16* __restrict__ qT){
  int i = blockIdx.x*256+threadIdx.x;
  float a = expf(sc[i]-M[0]);
  float b = expf(sc[N_NODES+i]-M[1]);
  pA[i]=a; pB[i]=b;
  qT[(size_t)512*N_NODES+i]=f2b(a);
  qT[(size_t)513*N_NODES+i]=f2b(b);
}

// sums 4 split-K slabs of G [4096][576]; dn cols 512/513; norm + sigmoid
__global__ void k_gfin(const float* __restrict__ G, float* __restrict__ gA,
                       float* __restrict__ gB){
  __shared__ float sm[4];
  __shared__ float tot;
  const size_t SL = (size_t)N_NODES*GCOLS;
  int n=blockIdx.x, c=threadIdx.x;
  int brv = blockIdx.y;
  int co = brv ? HIDC : 0, dcol = brv ? 513 : 512;
  float* g = brv ? gB : gA;
  size_t base = (size_t)n*GCOLS;
  float gp=0.f, dn=0.f;
  #pragma unroll
  for (int s=0;s<4;s++){ gp += G[base+co+c+s*SL]; dn += G[base+dcol+s*SL]; }
  gp /= (dn + 1e-16f);
  float v = gp*gp;
  #pragma unroll
  for (int o=32;o>0;o>>=1) v+=__shfl_down(v,o);
  if ((c&63)==0) sm[c>>6]=v;
  __syncthreads();
  if (c==0) tot = sm[0]+sm[1]+sm[2]+sm[3];
  __syncthreads();
  float nrm = sqrtf(tot);
  float x = gp/fmaxf(nrm,1e-12f);
  g[(size_t)n*HIDC+c]=1.f/(1.f+expf(-x));
}

// ---------------- discriminator ----------------
__global__ void k_disc(const float* __restrict__ z, const float* __restrict__ za,
                       const float* __restrict__ V, const float* __restrict__ Va,
                       const float* __restrict__ bbp, const float* __restrict__ biasp,
                       float* __restrict__ ret, float* __restrict__ ret_a){
  __shared__ float sm[16];
  int n=blockIdx.x, c=threadIdx.x;
  float ez = z[(size_t)n*HIDC+c], ea = za[(size_t)n*HIDC+c];
  float v  = V[(size_t)n*HIDC+c], va = Va[(size_t)n*HIDC+c];
  float p1=ez*v, p2=ea*v, p3=ea*va, p4=ez*va;
  #pragma unroll
  for (int o=32;o>0;o>>=1){
    p1+=__shfl_down(p1,o); p2+=__shfl_down(p2,o);
    p3+=__shfl_down(p3,o); p4+=__shfl_down(p4,o);
  }
  int lane=c&63, w=c>>6;
  if (lane==0){ sm[w]=p1; sm[4+w]=p2; sm[8+w]=p3; sm[12+w]=p4; }
  __syncthreads();
  if (c==0){
    float add = bbp[0]+biasp[0];
    ret[n*2+0]   = sm[0]+sm[1]+sm[2]+sm[3]   + add;
    ret[n*2+1]   = sm[4]+sm[5]+sm[6]+sm[7]   + add;
    ret_a[n*2+0] = sm[8]+sm[9]+sm[10]+sm[11] + add;
    ret_a[n*2+1] = sm[12]+sm[13]+sm[14]+sm[15] + add;
  }
}

extern "C" void kernel_launch(void* const* d_in, const int* in_sizes, int n_in,
                              void* d_out, int out_size, void* d_ws, size_t ws_size,
                              hipStream_t stream){
  (void)in_sizes; (void)n_in; (void)out_size; (void)ws_size;
  const float* feat   = (const float*)d_in[0];
  const float* feat_a = (const float*)d_in[1];
  const int*   ei     = (const int*)d_in[2];
  const float* ew     = (const float*)d_in[3];
  const int*   mask   = (const int*)d_in[4];
  const float* W1     = (const float*)d_in[5];
  const float* a_src1 = (const float*)d_in[6];
  const float* a_dst1 = (const float*)d_in[7];
  const float* b1     = (const float*)d_in[8];
  const float* W2     = (const float*)d_in[9];
  const float* a_src2 = (const float*)d_in[10];
  const float* a_dst2 = (const float*)d_in[11];
  const float* b2     = (const float*)d_in[12];
  const float* pw1    = (const float*)d_in[13];
  const float* pb1    = (const float*)d_in[14];
  const float* pw2    = (const float*)d_in[15];
  const float* pb2    = (const float*)d_in[16];
  const float* dw     = (const float*)d_in[17];
  const float* dbb    = (const float*)d_in[18];
  const float* dbias  = (const float*)d_in[19];

  float* out  = (float*)d_out;
  float* z    = out;
  float* hout = out + (size_t)N_NODES*HIDC;
  float* ret  = hout + (size_t)N_NODES*F_INF;
  float* ret_a= ret + (size_t)N_NODES*2;

  char* cur = (char*)d_ws;
  auto alloc = [&](size_t bytes)->void*{
    void* p = cur; cur += (bytes + 255) & ~(size_t)255; return p;
  };
  // SLB: time-shared — proj slabs (33.5MB) -> h2b (24MB) -> mask slabs (37.7MB)
  void* SLB = alloc((size_t)4*N_NODES*GCOLS*4);
  u16* W1T  = (u16*)alloc((size_t)HIDC*FPAD*2);
  u16* W2T  = (u16*)alloc((size_t)NPAD*HIDC*2);
  u16* pw1T = (u16*)alloc((size_t)POOLH*HIDC*2);
  u16* qT   = (u16*)alloc((size_t)GCOLS*N_NODES*2);
  u16* dwb  = (u16*)alloc((size_t)HIDC*HIDC*2);
  float* h1st = (float*)alloc((size_t)2*N_NODES*HIDC*4);
  float* za   = (float*)alloc((size_t)N_NODES*HIDC*4);
  float* Vst  = (float*)alloc((size_t)2*N_NODES*HIDC*4); // Hp slabs, then V;Va
  float* gv   = (float*)alloc((size_t)N_NODES*HIDC*4);
  float* gva  = (float*)alloc((size_t)N_NODES*HIDC*4);
  float* ss1 = (float*)alloc((size_t)2*N_NODES*4*4);
  float* sd1 = (float*)alloc((size_t)2*N_NODES*4*4);
  float* ss2 = (float*)alloc(N_NODES*4);
  float* sd2 = (float*)alloc(N_NODES*4);
  float* scAB = (float*)alloc((size_t)2*N_NODES*4);
  float* pvA = (float*)alloc(N_NODES*4);
  float* pvB = (float*)alloc(N_NODES*4);
  float* Mb  = (float*)alloc(256);
  int* deg    = (int*)alloc(N_NODES*4);
  int* off    = (int*)alloc((N_NODES+64)*4);
  int* cursor = (int*)alloc(N_NODES*4);
  int* csrc   = (int*)alloc(NEDGE*4);
  float* csw  = (float*)alloc(NEDGE*4);

  float* h1a = h1st + (size_t)N_NODES*HIDC;
  float* V   = Vst;
  float* Va  = Vst + (size_t)N_NODES*HIDC;
  (void)h1a;

  // ---- CSR build ----
  hipMemsetAsync(deg, 0, N_NODES*sizeof(int), stream);
  hipMemsetAsync(cursor, 0, N_NODES*sizeof(int), stream);
  hipMemsetAsync(qT + (size_t)514*N_NODES, 0, (size_t)(GCOLS-514)*N_NODES*2, stream);
  k_deg<<<NEDGE/256,256,0,stream>>>(ei+NEDGE, deg);
  k_scan<<<1,1024,0,stream>>>(deg, off);
  k_fill<<<NEDGE/256,256,0,stream>>>(ei, ew, off, cursor, csrc, csw);

  // ---- weight conversions ----
  k_trcvt<<<dim3(HIDC/32, FPAD/32),256,0,stream>>>(W1, W1T, F_INF, HIDC, FPAD, nullptr);
  k_trcvt<<<dim3(NPAD/32, HIDC/32),256,0,stream>>>(W2, W2T, HIDC, F_INF, HIDC, nullptr);
  k_trcvt<<<dim3(POOLH/32, HIDC/32),256,0,stream>>>(pw1, pw1T, HIDC, POOLH, HIDC, nullptr);
  k_cvt<<<HIDC*HIDC/4/256,256,0,stream>>>(dw, dwb, HIDC, HIDC, HIDC);

  // ---- stacked projection, split-K=4: slabs = [feat;feat_a] @ W1 ----
  k_mg<128,64,0,0><<<dim3(2*N_NODES/128, HIDC/64, 4),256,0,stream>>>(
      feat, feat_a, N_NODES, W1T, SLB, 2*N_NODES, HIDC, F_INF, F_INF, FPAD, HIDC, 768);
  k_hred<<<2*N_NODES,256,0,stream>>>((const float*)SLB, h1st, a_src1, a_dst1, ss1, sd1);

  // ---- GAT1 both branches (one launch) ----
  k_gat1<<<2*N_NODES,256,0,stream>>>(h1st, ss1, sd1, off, csrc, csw, b1, z, za);

  // ---- GAT2: h2 = z @ W2 (bf16 into SLB), then aggregate ----
  u16* h2b = (u16*)SLB;
  k_mg<128,128,0,1><<<dim3(N_NODES/128, NPAD/128, 1),256,0,stream>>>(
      z, z, N_NODES, W2T, h2b, N_NODES, NPAD, HIDC, HIDC, HIDC, NPAD, HIDC);
  k_scores2<<<N_NODES,256,0,stream>>>(h2b, a_src2, a_dst2, ss2, sd2);
  k_gat2<<<N_NODES,384,0,stream>>>(h2b, ss2, sd2, off, csrc, csw, b2, hout);

  // ---- pooling MLP as GEMM: Hp = [z;za] @ pw1 (split-K=2 into Vst) ----
  k_mg<128,64,0,0><<<dim3(2*N_NODES/128, POOLH/64, 2),256,0,stream>>>(
      z, za, N_NODES, pw1T, Vst, 2*N_NODES, POOLH, HIDC, HIDC, HIDC, POOLH, 128);
  k_score<<<2*N_NODES/4,256,0,stream>>>(Vst, pb1, pw2, pb2, scAB);
  k_maxred2<<<2,1024,0,stream>>>(scAB, Mb);
  k_p2<<<N_NODES/256,256,0,stream>>>(scAB, Mb, pvA, pvB, qT);
  k_trcvt<<<dim3(HIDC/32, N_NODES/32),256,0,stream>>>(z,  qT, N_NODES, HIDC, N_NODES, pvA);
  k_trcvt<<<dim3(HIDC/32, N_NODES/32),256,0,stream>>>(za, qT + (size_t)HIDC*N_NODES, N_NODES, HIDC, N_NODES, pvB);

  // ---- masked-softmax GEMM: G = Mask @ [q | qa | pA | pB], split-K=4 ----
  k_mg<128,64,1,0><<<dim3(N_NODES/128, GCOLS/64, 4),256,0,stream>>>(
      mask, mask, 2*N_NODES, qT, SLB, N_NODES, GCOLS, N_NODES, N_NODES, N_NODES, GCOLS, 1024);
  k_gfin<<<dim3(N_NODES,2),256,0,stream>>>((const float*)SLB, gv, gva);

  // ---- discriminator: [V;Va] = [gv;gva] @ dw^T ----
  k_mg<128,64,0,0><<<dim3(2*N_NODES/128, HIDC/64, 1),256,0,stream>>>(
      gv, gva, N_NODES, dwb, Vst, 2*N_NODES, HIDC, HIDC, HIDC, HIDC, HIDC, HIDC);
  k_disc<<<N_NODES,256,0,stream>>>(z, za, V, Va, dbb, dbias, ret, ret_a);
}

// Round 6
// 298.601 us; speedup vs baseline: 8.1066x; 1.1262x over previous
//
#include <hip/hip_runtime.h>
#include <cstdint>
#include <cstddef>

#define N_NODES 4096
#define F_INF   3000
#define FPAD    3008
#define NPAD    3072
#define HIDC    256
#define NEDGE   65536
#define POOLH   128
#define GCOLS   576   // 256 (branch1) + 256 (branchA) + dnA + dnB + pad

typedef unsigned short u16;
typedef __attribute__((ext_vector_type(8))) short bf16x8;
typedef __attribute__((ext_vector_type(8))) unsigned short us8;
typedef __attribute__((ext_vector_type(4))) unsigned int u32x4;
typedef __attribute__((ext_vector_type(4))) float f32x4;

__device__ inline float lrelu(float x){ return x > 0.f ? x : 0.2f*x; }
__device__ inline u16 f2b(float f){
  uint32_t x = __builtin_bit_cast(uint32_t, f);
  uint32_t r = (x + 0x7fffu + ((x >> 16) & 1u)) >> 16;
  return (u16)r;
}
__device__ inline float b2f(u16 u){
  uint32_t x = ((uint32_t)u) << 16;
  return __builtin_bit_cast(float, x);
}
// packed f32x2 -> bf16x2 (RTNE), one instruction
__device__ __forceinline__ uint32_t cvt2(float lo, float hi){
  uint32_t r;
  asm("v_cvt_pk_bf16_f32 %0, %1, %2" : "=v"(r) : "v"(lo), "v"(hi));
  return r;
}
// XOR swizzle for [row][64 bf16] tiles (128B rows): conflict-free b128 r/w.
__device__ __forceinline__ int swz(int row, int cb){
  return row*128 + (cb ^ ((row & 7) << 4));
}

// ---------------- CSR build ----------------
__global__ void k_deg(const int* __restrict__ dst, int* __restrict__ deg){
  int e = blockIdx.x*256 + threadIdx.x;
  if (e < NEDGE) atomicAdd(&deg[dst[e]], 1);
}

__global__ void k_scan(const int* __restrict__ deg, int* __restrict__ off){
  __shared__ int sm[1024];
  int tid = threadIdx.x;
  int v0=deg[tid*4], v1=deg[tid*4+1], v2=deg[tid*4+2], v3=deg[tid*4+3];
  int s = v0+v1+v2+v3;
  sm[tid]=s; __syncthreads();
  for (int d=1; d<1024; d<<=1){
    int t = (tid>=d)? sm[tid-d] : 0;
    __syncthreads();
    sm[tid] += t;
    __syncthreads();
  }
  int run = sm[tid]-s;
  off[tid*4+0]=run; run+=v0;
  off[tid*4+1]=run; run+=v1;
  off[tid*4+2]=run; run+=v2;
  off[tid*4+3]=run; run+=v3;
  if (tid==1023) off[N_NODES]=run;
}

__global__ void k_fill(const int* __restrict__ ei, const float* __restrict__ ew,
                       const int* __restrict__ off, int* __restrict__ cursor,
                       int* __restrict__ csr_src, float* __restrict__ csr_w){
  int e = blockIdx.x*256+threadIdx.x;
  if (e >= NEDGE) return;
  int d = ei[NEDGE + e];
  int slot = off[d] + atomicAdd(&cursor[d],1);
  csr_src[slot] = ei[e];
  csr_w[slot] = ew[e];
}

// ---------------- conversions ----------------
__global__ void k_cvt(const float* __restrict__ in, u16* __restrict__ out,
                      int R, int Cin, int Cout){
  size_t i = ((size_t)blockIdx.x*256 + threadIdx.x)*4;
  if (i >= (size_t)R*Cout) return;
  int r = (int)(i / Cout), c = (int)(i % Cout);
  ushort4 o;
  if (c + 3 < Cin){
    float4 v = *(const float4*)(in + (size_t)r*Cin + c);
    o.x=f2b(v.x); o.y=f2b(v.y); o.z=f2b(v.z); o.w=f2b(v.w);
  } else {
    float vs[4];
    #pragma unroll
    for (int j=0;j<4;j++) vs[j] = (c+j<Cin)? in[(size_t)r*Cin+c+j] : 0.f;
    o.x=f2b(vs[0]); o.y=f2b(vs[1]); o.z=f2b(vs[2]); o.w=f2b(vs[3]);
  }
  *(ushort4*)(out+i) = o;
}

// out[c][r] = in[r][c] * (scale?scale[r]:1), bf16, zero-pad outside [R][C].
__global__ void k_trcvt(const float* __restrict__ in, u16* __restrict__ out,
                        int R, int C, int OCols, const float* __restrict__ scale){
  __shared__ float t[32][33];
  int c0 = blockIdx.x*32, r0 = blockIdx.y*32;
  int tx = threadIdx.x & 31, ty = threadIdx.x >> 5;
  #pragma unroll
  for (int i=0;i<4;i++){
    int r = r0 + ty + i*8, c = c0 + tx;
    float v = (r<R && c<C) ? in[(size_t)r*C + c] : 0.f;
    if (scale && r<R) v *= scale[r];
    t[ty+i*8][tx] = v;
  }
  __syncthreads();
  #pragma unroll
  for (int i=0;i<4;i++){
    int c = c0 + ty + i*8, r = r0 + tx;
    out[(size_t)c*OCols + r] = f2b(t[tx][ty+i*8]);
  }
}

// ------- MFMA GEMM, T14 prefetch: reg-stage(+cvt) -> swizzled LDS -------
// C[M,N] = A[M,K] @ B^T, B [N][ldb] bf16 zero-padded. grid (M/BM, N/BN, SPLITK).
// ATYPE 0 = f32 (stacked pair split at srow), 1 = int32 0/1 mask -> bf16.
// C write: f32, bounded at nmax cols, optional bias (use only with gridDim.z==1).
template<int BM, int BN, int ATYPE>
__global__ __launch_bounds__(256) void k_mg(
    const void* __restrict__ A0v, const void* __restrict__ A1v, int srow,
    const u16* __restrict__ B, float* __restrict__ Cv,
    const float* __restrict__ bias,
    int M, int nmax, int K, int lda, int ldb, int ldc, int kcount){
  constexpr int WM = BM/2, WN = BN/2, MR = WM/16, NR = WN/16;
  constexpr int AP = BM/32, BP = BN/32;
  __shared__ __align__(16) u16 sA[BM*64];
  __shared__ __align__(16) u16 sB[BN*64];
  const int tid = threadIdx.x;
  const int bm = blockIdx.x*BM, bn = blockIdx.y*BN;
  const int lane = tid & 63, w = tid >> 6;
  const int wr = w >> 1, wc = w & 1;
  f32x4 acc[MR][NR] = {};

  const int kbeg = blockIdx.z * kcount;
  const int kend = min(K, kbeg + kcount);

  float afr[AP][8];   // ATYPE 0 staging regs
  int   air[AP][8];   // ATYPE 1 staging regs
  us8   brr[BP];      // B staging regs

  auto loadA = [&](int kk2, int rem2){
    #pragma unroll
    for (int p=0;p<AP;p++){
      int idx=(p*256+tid)*8, row=idx>>6, col=idx&63, grow=bm+row;
      if (ATYPE==0){
        const float* Ar = (grow<srow)? ((const float*)A0v+(size_t)grow*lda+kk2)
                                     : ((const float*)A1v+(size_t)(grow-srow)*lda+kk2);
        if (col+8<=rem2){
          float4 v0=*(const float4*)(Ar+col), v1=*(const float4*)(Ar+col+4);
          afr[p][0]=v0.x; afr[p][1]=v0.y; afr[p][2]=v0.z; afr[p][3]=v0.w;
          afr[p][4]=v1.x; afr[p][5]=v1.y; afr[p][6]=v1.z; afr[p][7]=v1.w;
        } else {
          #pragma unroll
          for (int j=0;j<8;j++) afr[p][j] = (col+j<rem2)? Ar[col+j] : 0.f;
        }
      } else {
        const int* Ar=(const int*)A0v+(size_t)grow*lda+kk2;
        if (col+8<=rem2){
          int4 v0=*(const int4*)(Ar+col), v1=*(const int4*)(Ar+col+4);
          air[p][0]=v0.x; air[p][1]=v0.y; air[p][2]=v0.z; air[p][3]=v0.w;
          air[p][4]=v1.x; air[p][5]=v1.y; air[p][6]=v1.z; air[p][7]=v1.w;
        } else {
          #pragma unroll
          for (int j=0;j<8;j++) air[p][j] = (col+j<rem2)? Ar[col+j] : 0;
        }
      }
    }
  };
  auto loadB = [&](int kk2){
    #pragma unroll
    for (int p=0;p<BP;p++){
      int idx=(p*256+tid)*8, row=idx>>6, col=idx&63;
      brr[p] = *(const us8*)(B+(size_t)(bn+row)*ldb+kk2+col);
    }
  };
  auto store = [&](){
    #pragma unroll
    for (int p=0;p<AP;p++){
      int idx=(p*256+tid)*8, row=idx>>6, col=idx&63;
      u32x4 o;
      if (ATYPE==0){
        o[0]=cvt2(afr[p][0],afr[p][1]); o[1]=cvt2(afr[p][2],afr[p][3]);
        o[2]=cvt2(afr[p][4],afr[p][5]); o[3]=cvt2(afr[p][6],afr[p][7]);
      } else {
        #pragma unroll
        for (int j=0;j<4;j++)
          o[j] = (uint32_t)air[p][2*j]*0x3F80u + (uint32_t)air[p][2*j+1]*0x3F800000u;
      }
      *(u32x4*)((char*)sA + swz(row, col*2)) = o;
    }
    #pragma unroll
    for (int p=0;p<BP;p++){
      int idx=(p*256+tid)*8, row=idx>>6, col=idx&63;
      *(us8*)((char*)sB + swz(row, col*2)) = brr[p];
    }
  };

  loadA(kbeg, kend-kbeg); loadB(kbeg);
  for (int kk=kbeg; kk<kend; kk+=64){
    store();
    __syncthreads();
    int kn = kk+64;
    if (kn < kend){ loadA(kn, kend-kn); loadB(kn); }  // prefetch: overlaps MFMA
    #pragma unroll
    for (int ks=0;ks<2;ks++){
      bf16x8 af[MR], bfr[NR];
      #pragma unroll
      for (int m=0;m<MR;m++)
        af[m] = *(const bf16x8*)((char*)sA + swz(wr*WM + m*16 + (lane&15), ks*64 + (lane>>4)*16));
      #pragma unroll
      for (int n=0;n<NR;n++)
        bfr[n] = *(const bf16x8*)((char*)sB + swz(wc*WN + n*16 + (lane&15), ks*64 + (lane>>4)*16));
      #pragma unroll
      for (int m=0;m<MR;m++)
        #pragma unroll
        for (int n=0;n<NR;n++)
          acc[m][n] = __builtin_amdgcn_mfma_f32_16x16x32_bf16(af[m], bfr[n], acc[m][n], 0,0,0);
    }
    __syncthreads();
  }

  const size_t slab = (size_t)blockIdx.z * (size_t)M * ldc;
  float* C = Cv + slab;
  const int rbase = bm + wr*WM + ((lane>>4)<<2);
  const int cbase = bn + wc*WN + (lane&15);
  #pragma unroll
  for (int n=0;n<NR;n++){
    int gcol = cbase + n*16;
    if (gcol >= nmax) continue;
    float bv = bias ? bias[gcol] : 0.f;
    #pragma unroll
    for (int m=0;m<MR;m++)
      #pragma unroll
      for (int j=0;j<4;j++)
        C[(size_t)(rbase + m*16 + j)*ldc + gcol] = acc[m][n][j] + bv;
  }
}

// ---------------- proj slab-reduce fused with GAT1 scores ----------------
__global__ void k_hred(const float* __restrict__ S, float* __restrict__ h,
                       const float* __restrict__ a_src, const float* __restrict__ a_dst,
                       float* __restrict__ ss, float* __restrict__ sd){
  const size_t SLP = (size_t)2*N_NODES*HIDC;
  int n = blockIdx.x, c = threadIdx.x;
  size_t i = (size_t)n*HIDC + c;
  float v = S[i] + S[i+SLP] + S[i+2*SLP] + S[i+3*SLP];
  h[i] = v;
  float vs = v*a_src[c], vd = v*a_dst[c];
  #pragma unroll
  for (int o=32;o>0;o>>=1){ vs += __shfl_down(vs,o); vd += __shfl_down(vd,o); }
  if ((c&63)==0){ int hh=c>>6; ss[n*4+hh]=vs; sd[n*4+hh]=vd; }
}

// ---------------- w_src/w_dst = W2 @ a2 (per output channel c) ----------------
__global__ void k_wvec(const float* __restrict__ W2, const float* __restrict__ a2s,
                       const float* __restrict__ a2d, float* __restrict__ wsrc,
                       float* __restrict__ wdst){
  __shared__ float sm[8];
  int c = blockIdx.x, t = threadIdx.x;
  const float* row = W2 + (size_t)c*F_INF;
  float vs=0.f, vd=0.f;
  for (int f=t; f<F_INF; f+=256){ float v=row[f]; vs+=v*a2s[f]; vd+=v*a2d[f]; }
  #pragma unroll
  for (int o=32;o>0;o>>=1){ vs+=__shfl_down(vs,o); vd+=__shfl_down(vd,o); }
  int lane=t&63, w=t>>6;
  if (lane==0){ sm[w]=vs; sm[4+w]=vd; }
  __syncthreads();
  if (t==0) wsrc[c]=sm[0]+sm[1]+sm[2]+sm[3];
  if (t==1) wdst[c]=sm[4]+sm[5]+sm[6]+sm[7];
}

// ---------------- GAT1 (both branches) + fused GAT2-score epilogue ----------------
__global__ void k_gat1(const float* __restrict__ h1st, const float* __restrict__ s_src,
                       const float* __restrict__ s_dst, const int* __restrict__ off,
                       const int* __restrict__ csr_src, const float* __restrict__ csr_w,
                       const float* __restrict__ b1, float* __restrict__ z,
                       float* __restrict__ za, const float* __restrict__ wsrc,
                       const float* __restrict__ wdst, float* __restrict__ ssz,
                       float* __restrict__ sdz){
  __shared__ float smz[8];
  int nb = blockIdx.x, c = threadIdx.x, h = c>>6;
  int n = nb & (N_NODES-1), br = nb >> 12;
  const float* hm = h1st + (size_t)br*N_NODES*HIDC;
  const float* ssp = s_src + (size_t)br*N_NODES*4;
  const float* sdp = s_dst + (size_t)br*N_NODES*4;
  float* zp = br ? za : z;
  int o0 = off[n], o1 = off[n+1];
  float sd = sdp[n*4+h];
  float m = -1e30f;
  for (int t=o0;t<o1;t++){
    int s = csr_src[t];
    m = fmaxf(m, lrelu(ssp[s*4+h]+sd));
  }
  float denom=0.f, acc=0.f;
  for (int t=o0;t<o1;t++){
    int s = csr_src[t];
    float wv = __expf(lrelu(ssp[s*4+h]+sd)-m)*csr_w[t];
    denom += wv;
    acc += wv * hm[(size_t)s*HIDC + c];
  }
  float res = acc/(denom+1e-16f) + b1[c];
  float zv = fmaxf(res, 0.f);
  zp[(size_t)n*HIDC+c] = zv;
  if (br==0){   // fused: GAT2 attention scores ssz[n]=z.wsrc, sdz[n]=z.wdst
    float vs = zv*wsrc[c], vd = zv*wdst[c];
    #pragma unroll
    for (int o=32;o>0;o>>=1){ vs+=__shfl_down(vs,o); vd+=__shfl_down(vd,o); }
    int lane=c&63, w=c>>6;
    if (lane==0){ smz[w]=vs; smz[4+w]=vd; }
    __syncthreads();
    if (c==0) ssz[n]=smz[0]+smz[1]+smz[2]+smz[3];
    if (c==1) sdz[n]=smz[4]+smz[5]+smz[6]+smz[7];
  }
}

// ---------------- GAT2 aggregation on z (256-wide) ----------------
__global__ void k_gatz(const float* __restrict__ z, const float* __restrict__ ssz,
                       const float* __restrict__ sdz, const int* __restrict__ off,
                       const int* __restrict__ csr_src, const float* __restrict__ csr_w,
                       float* __restrict__ agg){
  int n = blockIdx.x, c = threadIdx.x;
  int o0=off[n], o1=off[n+1];
  float sd = sdz[n];
  float m=-1e30f;
  for (int t=o0;t<o1;t++) m = fmaxf(m, lrelu(ssz[csr_src[t]]+sd));
  float denom=0.f, acc=0.f;
  for (int t=o0;t<o1;t++){
    int s=csr_src[t];
    float wv = __expf(lrelu(ssz[s]+sd)-m)*csr_w[t];
    denom += wv;
    acc += wv * z[(size_t)s*HIDC + c];
  }
  agg[(size_t)n*HIDC+c] = acc/(denom+1e-16f);
}

// ---------------- pooling: scores from Hp slabs (wave per row) ----------------
__global__ void k_score(const float* __restrict__ Hp, const float* __restrict__ b1,
                        const float* __restrict__ w2, const float* __restrict__ b2,
                        float* __restrict__ sc){
  const size_t SLP = (size_t)2*N_NODES*POOLH;
  int row = blockIdx.x*4 + (threadIdx.x>>6);
  int lane = threadIdx.x & 63;
  size_t base = (size_t)row*POOLH;
  float h0 = fmaxf(Hp[base+lane]    + Hp[base+lane+SLP]    + b1[lane],    0.f);
  float h1 = fmaxf(Hp[base+lane+64] + Hp[base+lane+64+SLP] + b1[lane+64], 0.f);
  float v = h0*w2[lane] + h1*w2[lane+64];
  #pragma unroll
  for (int o=32;o>0;o>>=1) v += __shfl_down(v,o);
  if (lane==0) sc[row] = v + b2[0];
}

__global__ void k_maxred2(const float* __restrict__ s, float* __restrict__ M){
  __shared__ float sm[16];
  int tid=threadIdx.x;
  const float* sp = s + (size_t)blockIdx.x*N_NODES;
  float m=-1e30f;
  for (int i=tid;i<N_NODES;i+=1024) m=fmaxf(m,sp[i]);
  #pragma unroll
  for (int o=32;o>0;o>>=1) m=fmaxf(m,__shfl_down(m,o));
  if ((tid&63)==0) sm[tid>>6]=m;
  __syncthreads();
  if (tid==0){
    float mm=sm[0];
    for (int i=1;i<16;i++) mm=fmaxf(mm,sm[i]);
    M[blockIdx.x]=mm;
  }
}

__global__ void k_p2(const float* __restrict__ sc, const float* __restrict__ M,
                     float* __restrict__ pA, float* __restrict__ pB,
                     u16* __restrict__ qT){
  int i = blockIdx.x*256+threadIdx.x;
  float a = __expf(sc[i]-M[0]);
  float b = __expf(sc[N_NODES+i]-M[1]);
  pA[i]=a; pB[i]=b;
  qT[(size_t)512*N_NODES+i]=f2b(a);
  qT[(size_t)513*N_NODES+i]=f2b(b);
}

// sums 4 split-K slabs of G [4096][576]; dn cols 512/513; norm + sigmoid
__global__ void k_gfin(const float* __restrict__ G, float* __restrict__ gA,
                       float* __restrict__ gB){
  __shared__ float sm[4];
  __shared__ float tot;
  const size_t SL = (size_t)N_NODES*GCOLS;
  int n=blockIdx.x, c=threadIdx.x;
  int brv = blockIdx.y;
  int co = brv ? HIDC : 0, dcol = brv ? 513 : 512;
  float* g = brv ? gB : gA;
  size_t base = (size_t)n*GCOLS;
  float gp=0.f, dn=0.f;
  #pragma unroll
  for (int s=0;s<4;s++){ gp += G[base+co+c+s*SL]; dn += G[base+dcol+s*SL]; }
  gp /= (dn + 1e-16f);
  float v = gp*gp;
  #pragma unroll
  for (int o=32;o>0;o>>=1) v+=__shfl_down(v,o);
  if ((c&63)==0) sm[c>>6]=v;
  __syncthreads();
  if (c==0) tot = sm[0]+sm[1]+sm[2]+sm[3];
  __syncthreads();
  float nrm = sqrtf(tot);
  float x = gp/fmaxf(nrm,1e-12f);
  g[(size_t)n*HIDC+c]=1.f/(1.f+__expf(-x));
}

// ---------------- discriminator ----------------
__global__ void k_disc(const float* __restrict__ z, const float* __restrict__ za,
                       const float* __restrict__ V, const float* __restrict__ Va,
                       const float* __restrict__ bbp, const float* __restrict__ biasp,
                       float* __restrict__ ret, float* __restrict__ ret_a){
  __shared__ float sm[16];
  int n=blockIdx.x, c=threadIdx.x;
  float ez = z[(size_t)n*HIDC+c], ea = za[(size_t)n*HIDC+c];
  float v  = V[(size_t)n*HIDC+c], va = Va[(size_t)n*HIDC+c];
  float p1=ez*v, p2=ea*v, p3=ea*va, p4=ez*va;
  #pragma unroll
  for (int o=32;o>0;o>>=1){
    p1+=__shfl_down(p1,o); p2+=__shfl_down(p2,o);
    p3+=__shfl_down(p3,o); p4+=__shfl_down(p4,o);
  }
  int lane=c&63, w=c>>6;
  if (lane==0){ sm[w]=p1; sm[4+w]=p2; sm[8+w]=p3; sm[12+w]=p4; }
  __syncthreads();
  if (c==0){
    float add = bbp[0]+biasp[0];
    ret[n*2+0]   = sm[0]+sm[1]+sm[2]+sm[3]   + add;
    ret[n*2+1]   = sm[4]+sm[5]+sm[6]+sm[7]   + add;
    ret_a[n*2+0] = sm[8]+sm[9]+sm[10]+sm[11] + add;
    ret_a[n*2+1] = sm[12]+sm[13]+sm[14]+sm[15] + add;
  }
}

extern "C" void kernel_launch(void* const* d_in, const int* in_sizes, int n_in,
                              void* d_out, int out_size, void* d_ws, size_t ws_size,
                              hipStream_t stream){
  (void)in_sizes; (void)n_in; (void)out_size; (void)ws_size;
  const float* feat   = (const float*)d_in[0];
  const float* feat_a = (const float*)d_in[1];
  const int*   ei     = (const int*)d_in[2];
  const float* ew     = (const float*)d_in[3];
  const int*   mask   = (const int*)d_in[4];
  const float* W1     = (const float*)d_in[5];
  const float* a_src1 = (const float*)d_in[6];
  const float* a_dst1 = (const float*)d_in[7];
  const float* b1     = (const float*)d_in[8];
  const float* W2     = (const float*)d_in[9];
  const float* a_src2 = (const float*)d_in[10];
  const float* a_dst2 = (const float*)d_in[11];
  const float* b2     = (const float*)d_in[12];
  const float* pw1    = (const float*)d_in[13];
  const float* pb1    = (const float*)d_in[14];
  const float* pw2    = (const float*)d_in[15];
  const float* pb2    = (const float*)d_in[16];
  const float* dw     = (const float*)d_in[17];
  const float* dbb    = (const float*)d_in[18];
  const float* dbias  = (const float*)d_in[19];

  float* out  = (float*)d_out;
  float* z    = out;
  float* hout = out + (size_t)N_NODES*HIDC;
  float* ret  = hout + (size_t)N_NODES*F_INF;
  float* ret_a= ret + (size_t)N_NODES*2;

  char* cur = (char*)d_ws;
  auto alloc = [&](size_t bytes)->void*{
    void* p = cur; cur += (bytes + 255) & ~(size_t)255; return p;
  };
  // SLB: time-shared — proj slabs (33.5MB) -> mask slabs (37.7MB)
  void* SLB = alloc((size_t)4*N_NODES*GCOLS*4);
  u16* W1T  = (u16*)alloc((size_t)HIDC*FPAD*2);
  u16* W2T  = (u16*)alloc((size_t)NPAD*HIDC*2);
  u16* pw1T = (u16*)alloc((size_t)POOLH*HIDC*2);
  u16* qT   = (u16*)alloc((size_t)GCOLS*N_NODES*2);
  u16* dwb  = (u16*)alloc((size_t)HIDC*HIDC*2);
  float* h1st = (float*)alloc((size_t)2*N_NODES*HIDC*4);
  float* za   = (float*)alloc((size_t)N_NODES*HIDC*4);
  float* agg  = (float*)alloc((size_t)N_NODES*HIDC*4);
  float* Vst  = (float*)alloc((size_t)2*N_NODES*HIDC*4); // Hp slabs, then V;Va
  float* gv   = (float*)alloc((size_t)N_NODES*HIDC*4);
  float* gva  = (float*)alloc((size_t)N_NODES*HIDC*4);
  float* ss1 = (float*)alloc((size_t)2*N_NODES*4*4);
  float* sd1 = (float*)alloc((size_t)2*N_NODES*4*4);
  float* ssz = (float*)alloc(N_NODES*4);
  float* sdz = (float*)alloc(N_NODES*4);
  float* wsrc= (float*)alloc(HIDC*4);
  float* wdst= (float*)alloc(HIDC*4);
  float* scAB = (float*)alloc((size_t)2*N_NODES*4);
  float* pvA = (float*)alloc(N_NODES*4);
  float* pvB = (float*)alloc(N_NODES*4);
  float* Mb  = (float*)alloc(256);
  int* deg    = (int*)alloc(N_NODES*4);
  int* off    = (int*)alloc((N_NODES+64)*4);
  int* cursor = (int*)alloc(N_NODES*4);
  int* csrc   = (int*)alloc(NEDGE*4);
  float* csw  = (float*)alloc(NEDGE*4);

  float* V   = Vst;
  float* Va  = Vst + (size_t)N_NODES*HIDC;

  // ---- CSR build + independent small prep ----
  hipMemsetAsync(deg, 0, N_NODES*sizeof(int), stream);
  hipMemsetAsync(cursor, 0, N_NODES*sizeof(int), stream);
  hipMemsetAsync(qT + (size_t)514*N_NODES, 0, (size_t)(GCOLS-514)*N_NODES*2, stream);
  k_deg<<<NEDGE/256,256,0,stream>>>(ei+NEDGE, deg);
  k_scan<<<1,1024,0,stream>>>(deg, off);
  k_fill<<<NEDGE/256,256,0,stream>>>(ei, ew, off, cursor, csrc, csw);
  k_wvec<<<HIDC,256,0,stream>>>(W2, a_src2, a_dst2, wsrc, wdst);

  // ---- weight conversions ----
  k_trcvt<<<dim3(HIDC/32, FPAD/32),256,0,stream>>>(W1, W1T, F_INF, HIDC, FPAD, nullptr);
  k_trcvt<<<dim3(NPAD/32, HIDC/32),256,0,stream>>>(W2, W2T, HIDC, F_INF, HIDC, nullptr);
  k_trcvt<<<dim3(POOLH/32, HIDC/32),256,0,stream>>>(pw1, pw1T, HIDC, POOLH, HIDC, nullptr);
  k_cvt<<<HIDC*HIDC/4/256,256,0,stream>>>(dw, dwb, HIDC, HIDC, HIDC);

  // ---- stacked projection, split-K=4: slabs = [feat;feat_a] @ W1 ----
  k_mg<64,64,0><<<dim3(2*N_NODES/64, HIDC/64, 4),256,0,stream>>>(
      feat, feat_a, N_NODES, W1T, (float*)SLB, nullptr,
      2*N_NODES, HIDC, F_INF, F_INF, FPAD, HIDC, 768);
  k_hred<<<2*N_NODES,256,0,stream>>>((const float*)SLB, h1st, a_src1, a_dst1, ss1, sd1);

  // ---- GAT1 both branches + fused GAT2 scores ----
  k_gat1<<<2*N_NODES,256,0,stream>>>(h1st, ss1, sd1, off, csrc, csw, b1, z, za,
                                     wsrc, wdst, ssz, sdz);

  // ---- GAT2: aggregate z, then hout = agg @ W2 + b2 ----
  k_gatz<<<N_NODES,256,0,stream>>>(z, ssz, sdz, off, csrc, csw, agg);
  k_mg<128,64,0><<<dim3(N_NODES/128, FPAD/64, 1),256,0,stream>>>(
      agg, agg, N_NODES, W2T, hout, b2,
      N_NODES, F_INF, HIDC, HIDC, HIDC, F_INF, HIDC);

  // ---- pooling MLP as GEMM: Hp = [z;za] @ pw1 (split-K=2 into Vst) ----
  k_mg<64,64,0><<<dim3(2*N_NODES/64, POOLH/64, 2),256,0,stream>>>(
      z, za, N_NODES, pw1T, Vst, nullptr,
      2*N_NODES, POOLH, HIDC, HIDC, HIDC, POOLH, 128);
  k_score<<<2*N_NODES/4,256,0,stream>>>(Vst, pb1, pw2, pb2, scAB);
  k_maxred2<<<2,1024,0,stream>>>(scAB, Mb);
  k_p2<<<N_NODES/256,256,0,stream>>>(scAB, Mb, pvA, pvB, qT);
  k_trcvt<<<dim3(HIDC/32, N_NODES/32),256,0,stream>>>(z,  qT, N_NODES, HIDC, N_NODES, pvA);
  k_trcvt<<<dim3(HIDC/32, N_NODES/32),256,0,stream>>>(za, qT + (size_t)HIDC*N_NODES, N_NODES, HIDC, N_NODES, pvB);

  // ---- masked-softmax GEMM: G = Mask @ [q | qa | pA | pB], split-K=4 ----
  k_mg<64,64,1><<<dim3(N_NODES/64, GCOLS/64, 4),256,0,stream>>>(
      mask, mask, 2*N_NODES, qT, (float*)SLB, nullptr,
      N_NODES, GCOLS, N_NODES, N_NODES, N_NODES, GCOLS, 1024);
  k_gfin<<<dim3(N_NODES,2),256,0,stream>>>((const float*)SLB, gv, gva);

  // ---- discriminator: [V;Va] = [gv;gva] @ dw^T ----
  k_mg<64,64,0><<<dim3(2*N_NODES/64, HIDC/64, 1),256,0,stream>>>(
      gv, gva, N_NODES, dwb, Vst, nullptr,
      2*N_NODES, HIDC, HIDC, HIDC, HIDC, HIDC, HIDC);
  k_disc<<<N_NODES,256,0,stream>>>(z, za, V, Va, dbb, dbias, ret, ret_a);
}